// Round 3
// baseline (18565.294 us; speedup 1.0000x reference)
//
#include <hip/hip_runtime.h>
#include <hip/hip_bf16.h>
#include <cstddef>

typedef __hip_bfloat16 bf16;

constexpr int H = 80, W = 96, T = 112;
constexpr int N = H * W * T;               // 860160
constexpr int Hh = 40, Wh = 48, Th = 56;
constexpr int Nh = Hh * Wh * Th;           // 107520
constexpr int PH = 84, PW = 100, PT = 116; // box3(y, pad=3) dims
constexpr int NPF = PH * PW * PT;          // 974400

static __device__ __forceinline__ float b2f(bf16 v) { return __bfloat162float(v); }
static __device__ __forceinline__ bf16  f2b(float v) { return __float2bfloat16(v); }

// ---- weight transpose: w[cout][cin][27] (f32) -> wT[(cin*27+tap)][cout] (f32, cout contiguous)
__global__ __launch_bounds__(256) void wtrans_kernel(const float* __restrict__ w,
                                                     float* __restrict__ out,
                                                     int Cout, int Cin)
{
    int idx = blockIdx.x * 256 + threadIdx.x;
    int total = Cout * Cin * 27;
    if (idx >= total) return;
    int tap  = idx % 27;
    int rest = idx / 27;
    int cin  = rest % Cin;
    int cout = rest / Cin;
    out[(cin * 27 + tap) * Cout + cout] = w[idx];
}

// ---- all biases -> one f32 array: [0,59)=b1a [59,75)=b1b [75,91)=b2a [91,107)=b2b [107,110)=bf
__global__ __launch_bounds__(128) void bias_kernel(const float* __restrict__ b1a, const float* __restrict__ b1b,
                                                   const float* __restrict__ b2a, const float* __restrict__ b2b,
                                                   const float* __restrict__ bff, float* __restrict__ out)
{
    int i = threadIdx.x;
    if      (i < 59)  out[i] = b1a[i];
    else if (i < 75)  out[i] = b1b[i - 59];
    else if (i < 91)  out[i] = b2a[i - 75];
    else if (i < 107) out[i] = b2b[i - 91];
    else if (i < 110) out[i] = bff[i - 107];
}

// ---- flow*2 then trilinear upsample (align_corners=True), (3,40,48,56) -> (3,80,96,112) f32
__global__ __launch_bounds__(256) void upsample_kernel(const float* __restrict__ flow,
                                                       float* __restrict__ flow_up)
{
    int idx = blockIdx.x * 256 + threadIdx.x;
    if (idx >= 3 * N) return;
    int c = idx / N, v = idx % N;
    int t = v % T; int hw = v / T; int w = hw % W; int h = hw / W;
    float ph = (float)h * ((float)(Hh - 1) / (float)(H - 1));
    float pw = (float)w * ((float)(Wh - 1) / (float)(W - 1));
    float pt = (float)t * ((float)(Th - 1) / (float)(T - 1));
    int i0 = min((int)ph, Hh - 2); float fh = ph - (float)i0;
    int j0 = min((int)pw, Wh - 2); float fw = pw - (float)j0;
    int k0 = min((int)pt, Th - 2); float ft = pt - (float)k0;
    const float* fp = flow + (size_t)c * Nh;
    auto L = [&](int a, int b, int d) -> float {
        return 2.0f * fp[((size_t)a * Wh + b) * Th + d];
    };
    float v000 = L(i0, j0, k0),     v001 = L(i0, j0, k0 + 1);
    float v010 = L(i0, j0 + 1, k0), v011 = L(i0, j0 + 1, k0 + 1);
    float v100 = L(i0 + 1, j0, k0),     v101 = L(i0 + 1, j0, k0 + 1);
    float v110 = L(i0 + 1, j0 + 1, k0), v111 = L(i0 + 1, j0 + 1, k0 + 1);
    float val = (1.f - fh) * ((1.f - fw) * ((1.f - ft) * v000 + ft * v001)
                            +        fw  * ((1.f - ft) * v010 + ft * v011))
              +        fh  * ((1.f - fw) * ((1.f - ft) * v100 + ft * v101)
                            +        fw  * ((1.f - ft) * v110 + ft * v111));
    flow_up[idx] = val;
}

// ---- warp x by flow_up (grid_sample trilinear, zeros padding) -> stack ch 0..15; copy y -> stack ch 43..58
__global__ __launch_bounds__(256) void warp_kernel(const float* __restrict__ x, const float* __restrict__ y,
                                                   const float* __restrict__ flow_up,
                                                   bf16* __restrict__ stack)
{
    int v = blockIdx.x * 256 + threadIdx.x;
    if (v >= N) return;
    int t = v % T; int hw = v / T; int w = hw % W; int h = hw / W;
    float cx = (float)h + flow_up[v];
    float cy = (float)w + flow_up[N + v];
    float cz = (float)t + flow_up[2 * N + v];
    float fx0 = floorf(cx), fy0 = floorf(cy), fz0 = floorf(cz);
    float fx = cx - fx0, fy = cy - fy0, fz = cz - fz0;
    int ix = (int)fx0, iy = (int)fy0, iz = (int)fz0;

    float wc[8];
    int   oc[8];
    #pragma unroll
    for (int c8 = 0; c8 < 8; c8++) {
        int dx = (c8 >> 2) & 1, dy = (c8 >> 1) & 1, dz = c8 & 1;
        int ax = ix + dx, ay = iy + dy, az = iz + dz;
        bool ok = ((unsigned)ax < (unsigned)H) && ((unsigned)ay < (unsigned)W) && ((unsigned)az < (unsigned)T);
        float wt = (dx ? fx : 1.f - fx) * (dy ? fy : 1.f - fy) * (dz ? fz : 1.f - fz);
        wc[c8] = ok ? wt : 0.f;
        int cax = min(max(ax, 0), H - 1);
        int cay = min(max(ay, 0), W - 1);
        int caz = min(max(az, 0), T - 1);
        oc[c8] = (cax * W + cay) * T + caz;
    }
    #pragma unroll 1
    for (int c = 0; c < 16; c++) {
        const float* xp = x + (size_t)c * N;
        float s = 0.f;
        #pragma unroll
        for (int c8 = 0; c8 < 8; c8++) s += wc[c8] * xp[oc[c8]];
        stack[(size_t)c * N + v] = f2b(s);
        stack[(size_t)(43 + c) * N + v] = f2b(y[(size_t)c * N + v]);
    }
}

// ---- pm = box3(xw, pad=1): 27-neighbor zero-padded sum, (16,H,W,T), bf16 in/out
__global__ __launch_bounds__(256) void pm_kernel(const bf16* __restrict__ xw, bf16* __restrict__ pm)
{
    int idx = blockIdx.x * 256 + threadIdx.x;
    if (idx >= 16 * N) return;
    int c = idx / N, v = idx % N;
    int t = v % T; int hw = v / T; int w = hw % W; int h = hw / W;
    const bf16* ip = xw + (size_t)c * N;
    float s = 0.f;
    #pragma unroll
    for (int dh = -1; dh <= 1; dh++)
    #pragma unroll
    for (int dw = -1; dw <= 1; dw++)
    #pragma unroll
    for (int dt = -1; dt <= 1; dt++) {
        int hh = h + dh, ww = w + dw, tt = t + dt;
        bool ok = ((unsigned)hh < (unsigned)H) && ((unsigned)ww < (unsigned)W) && ((unsigned)tt < (unsigned)T);
        int off = ok ? ((hh * W + ww) * T + tt) : 0;
        s += ok ? b2f(ip[off]) : 0.f;
    }
    pm[idx] = f2b(s);
}

// ---- pf = box3(y, pad=3): out (16,84,100,116) bf16, pf[a][b][d] = sum y[a-3..a-1][b-3..b-1][d-3..d-1]
__global__ __launch_bounds__(256) void pf_kernel(const float* __restrict__ y, bf16* __restrict__ pf)
{
    int idx = blockIdx.x * 256 + threadIdx.x;
    if (idx >= 16 * NPF) return;
    int c = idx / NPF, r = idx % NPF;
    int d = r % PT; int ab = r / PT; int b = ab % PW; int a = ab / PW;
    const float* ip = y + (size_t)c * N;
    float s = 0.f;
    #pragma unroll
    for (int da = 0; da < 3; da++)
    #pragma unroll
    for (int db = 0; db < 3; db++)
    #pragma unroll
    for (int dd = 0; dd < 3; dd++) {
        int hh = a - 3 + da, ww = b - 3 + db, tt = d - 3 + dd;
        bool ok = ((unsigned)hh < (unsigned)H) && ((unsigned)ww < (unsigned)W) && ((unsigned)tt < (unsigned)T);
        int off = ok ? ((hh * W + ww) * T + tt) : 0;
        s += ok ? ip[off] : 0.f;
    }
    pf[idx] = f2b(s);
}

// ---- corr[i*9+j*3+k][v] = (1/27) * sum_c pm[c][v] * pf[c][2i+h][2j+w][2k+t] -> stack ch 16..42
__global__ __launch_bounds__(256) void corr_kernel(const bf16* __restrict__ pm, const bf16* __restrict__ pf,
                                                   bf16* __restrict__ corr_out)
{
    int v = blockIdx.x * 256 + threadIdx.x;
    if (v >= N) return;
    int t = v % T; int hw = v / T; int w = hw % W; int h = hw / W;
    float pmv[16];
    #pragma unroll
    for (int c = 0; c < 16; c++) pmv[c] = b2f(pm[(size_t)c * N + v]);
    #pragma unroll 1
    for (int i = 0; i < 3; i++)
    #pragma unroll 1
    for (int j = 0; j < 3; j++)
    #pragma unroll 1
    for (int k = 0; k < 3; k++) {
        size_t base = ((size_t)(2 * i + h) * PW + (2 * j + w)) * PT + (2 * k + t);
        float s = 0.f;
        #pragma unroll
        for (int c = 0; c < 16; c++) s += pmv[c] * b2f(pf[(size_t)c * NPF + base]);
        corr_out[(size_t)(i * 9 + j * 3 + k) * N + v] = f2b(s * (1.f / 27.f));
    }
}

// ---- generic 3^3 conv, padding 1. in: (CIN,H,W,T) bf16; wT: [(cin*27+tap)][COUT] f32 (wave-uniform ->
// scalar loads feeding v_fmac with SGPR operand). OUT_F32: write f32 (final output), else bf16.
// ADD2: val = in+in2 (h+res).
template <int CIN, int COUT, bool RELU, bool ADD2, bool OUT_F32>
__global__ __launch_bounds__(256) void conv3_kernel(const bf16* __restrict__ in,
                                                    const bf16* __restrict__ in2,
                                                    const float* __restrict__ wT,
                                                    const float* __restrict__ bias,
                                                    void* __restrict__ out_p)
{
    int v = blockIdx.x * 256 + threadIdx.x;
    if (v >= N) return;
    int t = v % T; int hw = v / T; int w = hw % W; int h = hw / W;
    float acc[COUT];
    #pragma unroll
    for (int o = 0; o < COUT; o++) acc[o] = bias[o];

    #pragma unroll 1
    for (int ci = 0; ci < CIN; ci++) {
        const bf16* ip  = in + (size_t)ci * N;
        const bf16* ip2 = ADD2 ? (in2 + (size_t)ci * N) : nullptr;
        #pragma unroll
        for (int dh = 0; dh < 3; dh++)
        #pragma unroll
        for (int dw = 0; dw < 3; dw++)
        #pragma unroll
        for (int dt = 0; dt < 3; dt++) {
            int hh = h + dh - 1, ww = w + dw - 1, tt = t + dt - 1;
            bool ok = ((unsigned)hh < (unsigned)H) && ((unsigned)ww < (unsigned)W) && ((unsigned)tt < (unsigned)T);
            int off = ok ? ((hh * W + ww) * T + tt) : 0;
            float val = 0.f;
            if (ok) {
                val = b2f(ip[off]);
                if (ADD2) val += b2f(ip2[off]);
            }
            const float* wp = wT + ((size_t)ci * 27 + (dh * 9 + dw * 3 + dt)) * COUT;
            #pragma unroll
            for (int o = 0; o < COUT; o++) acc[o] += wp[o] * val;
        }
    }
    #pragma unroll
    for (int o = 0; o < COUT; o++) {
        float r = acc[o];
        if (RELU) r = fmaxf(r, 0.f);
        if (OUT_F32) ((float*)out_p)[(size_t)o * N + v] = r;
        else         ((bf16*)out_p)[(size_t)o * N + v] = f2b(r);
    }
}

extern "C" void kernel_launch(void* const* d_in, const int* in_sizes, int n_in,
                              void* d_out, int out_size, void* d_ws, size_t ws_size,
                              hipStream_t stream)
{
    (void)in_sizes; (void)n_in; (void)out_size; (void)ws_size;
    const float* x_p   = (const float*)d_in[0];
    const float* y_p   = (const float*)d_in[1];
    const float* flow_p= (const float*)d_in[2];
    const float* w1a_p = (const float*)d_in[3];
    const float* b1a_p = (const float*)d_in[4];
    const float* w1b_p = (const float*)d_in[5];
    const float* b1b_p = (const float*)d_in[6];
    const float* w2a_p = (const float*)d_in[7];
    const float* b2a_p = (const float*)d_in[8];
    const float* w2b_p = (const float*)d_in[9];
    const float* b2b_p = (const float*)d_in[10];
    const float* wf_p  = (const float*)d_in[11];
    const float* bf_p  = (const float*)d_in[12];

    // ---- workspace layout (bytes), total ~203.6 MB (194.1 MiB) — fit proven in round 2 ----
    // [0,    59NB)  region A: stack (59N bf16). After conv1a, A is dead and is reused for
    //               hbuf (+0, 16N), t2 (+16NB), res (+32NB).
    // [59NB, 118NB) region B: buf1 (59N bf16, conv1a output). Before conv1a runs, B holds
    //               pm (+0, 16N bf16), pf (+16NB, 16*NPF bf16), flow_up (after pf, 3N f32)
    //               — all dead before B is written by conv1a.
    // [118NB, ...)  f32 weights + biases (~540 KB).
    char* wsb = (char*)d_ws;
    const size_t NB = (size_t)N * 2;            // bytes per N bf16
    bf16* stack   = (bf16*)wsb;                                   // 59N
    bf16* buf1    = (bf16*)(wsb + 59 * NB);                       // 59N
    bf16* pm      = buf1;                                         // 16N (dead before buf1 written)
    bf16* pf      = (bf16*)(wsb + 59 * NB + 16 * NB);             // 16*NPF
    float* flow_up= (float*)(wsb + 59 * NB + 16 * NB + (size_t)16 * NPF * 2); // 3N f32
    bf16* hbuf    = stack;                                        // 16N (stack dead after conv1a)
    bf16* t2buf   = (bf16*)(wsb + 16 * NB);                       // 16N
    bf16* resbuf  = (bf16*)(wsb + 32 * NB);                       // 16N
    float* wT1a   = (float*)(wsb + 118 * NB);
    float* wT1b   = wT1a + 59 * 27 * 59;
    float* wT2a   = wT1b + 59 * 27 * 16;
    float* wT2b   = wT2a + 16 * 27 * 16;
    float* wTf    = wT2b + 16 * 27 * 16;
    float* biasf  = wTf + 16 * 27 * 3;                            // 110 floats

    int nb;
    nb = (59 * 59 * 27 + 255) / 256; wtrans_kernel<<<nb, 256, 0, stream>>>(w1a_p, wT1a, 59, 59);
    nb = (16 * 59 * 27 + 255) / 256; wtrans_kernel<<<nb, 256, 0, stream>>>(w1b_p, wT1b, 16, 59);
    nb = (16 * 16 * 27 + 255) / 256; wtrans_kernel<<<nb, 256, 0, stream>>>(w2a_p, wT2a, 16, 16);
    nb = (16 * 16 * 27 + 255) / 256; wtrans_kernel<<<nb, 256, 0, stream>>>(w2b_p, wT2b, 16, 16);
    nb = (3 * 16 * 27 + 255) / 256;  wtrans_kernel<<<nb, 256, 0, stream>>>(wf_p,  wTf,  3, 16);
    bias_kernel<<<1, 128, 0, stream>>>(b1a_p, b1b_p, b2a_p, b2b_p, bf_p, biasf);

    upsample_kernel<<<(3 * N + 255) / 256, 256, 0, stream>>>(flow_p, flow_up);
    warp_kernel<<<(N + 255) / 256, 256, 0, stream>>>(x_p, y_p, flow_up, stack);
    pm_kernel<<<(16 * N + 255) / 256, 256, 0, stream>>>(stack, pm);
    pf_kernel<<<(16 * NPF + 255) / 256, 256, 0, stream>>>(y_p, pf);
    corr_kernel<<<(N + 255) / 256, 256, 0, stream>>>(pm, pf, stack + (size_t)16 * N);

    conv3_kernel<59, 59, false, false, false><<<N / 256, 256, 0, stream>>>(stack, nullptr, wT1a, biasf + 0,   buf1);
    conv3_kernel<59, 16, true,  false, false><<<N / 256, 256, 0, stream>>>(buf1,  nullptr, wT1b, biasf + 59,  hbuf);
    conv3_kernel<16, 16, false, false, false><<<N / 256, 256, 0, stream>>>(hbuf,  nullptr, wT2a, biasf + 75,  t2buf);
    conv3_kernel<16, 16, true,  false, false><<<N / 256, 256, 0, stream>>>(t2buf, nullptr, wT2b, biasf + 91,  resbuf);
    conv3_kernel<16, 3,  false, true,  true ><<<N / 256, 256, 0, stream>>>(hbuf,  resbuf,  wTf,  biasf + 107, d_out);
}

// Round 4
// 2421.182 us; speedup vs baseline: 7.6679x; 7.6679x over previous
//
#include <hip/hip_runtime.h>
#include <hip/hip_bf16.h>
#include <cstddef>

typedef __hip_bfloat16 bf16;
typedef __attribute__((ext_vector_type(8))) short short8;   // 8 bf16 = one MFMA A/B frag
typedef __attribute__((ext_vector_type(4))) float f32x4;    // MFMA 16x16 accumulator

constexpr int H = 80, W = 96, T = 112;
constexpr int N = H * W * T;               // 860160
constexpr int WT = W * T;                  // 10752
constexpr int Hh = 40, Wh = 48, Th = 56;
constexpr int Nh = Hh * Wh * Th;
constexpr int PH = 84, PW = 100, PT = 116;
constexpr int NPF = PH * PW * PT;          // 974400

static __device__ __forceinline__ float b2f(bf16 v) { return __bfloat162float(v); }
static __device__ __forceinline__ bf16  f2b(float v) { return __float2bfloat16(v); }

// ================= weight build: w[COUT][CIN][27] f32 -> frag-order bf16 =================
// wb[((tap*KC_TOT+kc)*NT_TOT+nt)*64 + lane][j] = w[o=nt*16+(lane&15)][cin=kc*32+(lane>>4)*8+j][tap]
__global__ __launch_bounds__(256) void wbuild_kernel(const float* __restrict__ w, bf16* __restrict__ wb,
                                                     int COUT, int CIN, int KC_TOT, int NT_TOT)
{
    int idx = blockIdx.x * 256 + threadIdx.x;
    int total = 27 * KC_TOT * NT_TOT * 512;
    if (idx >= total) return;
    int j    = idx & 7;
    int lane = (idx >> 3) & 63;
    int rest = idx >> 9;
    int nt   = rest % NT_TOT; rest /= NT_TOT;
    int kc   = rest % KC_TOT;
    int tap  = rest / KC_TOT;
    int o    = nt * 16 + (lane & 15);
    int cin  = kc * 32 + (lane >> 4) * 8 + j;
    float val = (o < COUT && cin < CIN) ? w[((size_t)o * CIN + cin) * 27 + tap] : 0.f;
    wb[idx] = f2b(val);
}

// ---- padded biases (zeros in pads): [0,64) b1a | [64,96) b1b | [96,128) b2a | [128,160) b2b | [160,176) bf
__global__ __launch_bounds__(256) void bias_kernel(const float* __restrict__ b1a, const float* __restrict__ b1b,
                                                   const float* __restrict__ b2a, const float* __restrict__ b2b,
                                                   const float* __restrict__ bff, float* __restrict__ out)
{
    int i = threadIdx.x;
    if (i < 64)       out[i] = (i < 59) ? b1a[i] : 0.f;
    else if (i < 96)  { int j = i - 64;  out[i] = (j < 16) ? b1b[j] : 0.f; }
    else if (i < 128) { int j = i - 96;  out[i] = (j < 16) ? b2a[j] : 0.f; }
    else if (i < 160) { int j = i - 128; out[i] = (j < 16) ? b2b[j] : 0.f; }
    else if (i < 176) { int j = i - 160; out[i] = (j < 3)  ? bff[j] : 0.f; }
}

__global__ __launch_bounds__(64) void zp_kernel(unsigned* __restrict__ zp)
{
    zp[threadIdx.x] = 0u;   // 256 B of zeros
}

// ================= pre-conv pipeline =================
__global__ __launch_bounds__(256) void upsample_kernel(const float* __restrict__ flow,
                                                       float* __restrict__ flow_up)
{
    int idx = blockIdx.x * 256 + threadIdx.x;
    if (idx >= 3 * N) return;
    int c = idx / N, v = idx % N;
    int t = v % T; int hw = v / T; int w = hw % W; int h = hw / W;
    float ph = (float)h * ((float)(Hh - 1) / (float)(H - 1));
    float pw = (float)w * ((float)(Wh - 1) / (float)(W - 1));
    float pt = (float)t * ((float)(Th - 1) / (float)(T - 1));
    int i0 = min((int)ph, Hh - 2); float fh = ph - (float)i0;
    int j0 = min((int)pw, Wh - 2); float fw = pw - (float)j0;
    int k0 = min((int)pt, Th - 2); float ft = pt - (float)k0;
    const float* fp = flow + (size_t)c * Nh;
    auto L = [&](int a, int b, int d) -> float {
        return 2.0f * fp[((size_t)a * Wh + b) * Th + d];
    };
    float v000 = L(i0, j0, k0),     v001 = L(i0, j0, k0 + 1);
    float v010 = L(i0, j0 + 1, k0), v011 = L(i0, j0 + 1, k0 + 1);
    float v100 = L(i0 + 1, j0, k0),     v101 = L(i0 + 1, j0, k0 + 1);
    float v110 = L(i0 + 1, j0 + 1, k0), v111 = L(i0 + 1, j0 + 1, k0 + 1);
    float val = (1.f - fh) * ((1.f - fw) * ((1.f - ft) * v000 + ft * v001)
                            +        fw  * ((1.f - ft) * v010 + ft * v011))
              +        fh  * ((1.f - fw) * ((1.f - ft) * v100 + ft * v101)
                            +        fw  * ((1.f - ft) * v110 + ft * v111));
    flow_up[idx] = val;
}

// warp -> xw planar bf16 [16][N]
__global__ __launch_bounds__(256) void warp_kernel(const float* __restrict__ x,
                                                   const float* __restrict__ flow_up,
                                                   bf16* __restrict__ xw)
{
    int v = blockIdx.x * 256 + threadIdx.x;
    if (v >= N) return;
    int t = v % T; int hw = v / T; int w = hw % W; int h = hw / W;
    float cx = (float)h + flow_up[v];
    float cy = (float)w + flow_up[N + v];
    float cz = (float)t + flow_up[2 * N + v];
    float fx0 = floorf(cx), fy0 = floorf(cy), fz0 = floorf(cz);
    float fx = cx - fx0, fy = cy - fy0, fz = cz - fz0;
    int ix = (int)fx0, iy = (int)fy0, iz = (int)fz0;

    float wc[8];
    int   oc[8];
    #pragma unroll
    for (int c8 = 0; c8 < 8; c8++) {
        int dx = (c8 >> 2) & 1, dy = (c8 >> 1) & 1, dz = c8 & 1;
        int ax = ix + dx, ay = iy + dy, az = iz + dz;
        bool ok = ((unsigned)ax < (unsigned)H) && ((unsigned)ay < (unsigned)W) && ((unsigned)az < (unsigned)T);
        float wt = (dx ? fx : 1.f - fx) * (dy ? fy : 1.f - fy) * (dz ? fz : 1.f - fz);
        wc[c8] = ok ? wt : 0.f;
        int cax = min(max(ax, 0), H - 1);
        int cay = min(max(ay, 0), W - 1);
        int caz = min(max(az, 0), T - 1);
        oc[c8] = (cax * W + cay) * T + caz;
    }
    #pragma unroll 1
    for (int c = 0; c < 16; c++) {
        const float* xp = x + (size_t)c * N;
        float s = 0.f;
        #pragma unroll
        for (int c8 = 0; c8 < 8; c8++) s += wc[c8] * xp[oc[c8]];
        xw[(size_t)c * N + v] = f2b(s);
    }
}

__global__ __launch_bounds__(256) void pm_kernel(const bf16* __restrict__ xw, bf16* __restrict__ pm)
{
    int idx = blockIdx.x * 256 + threadIdx.x;
    if (idx >= 16 * N) return;
    int c = idx / N, v = idx % N;
    int t = v % T; int hw = v / T; int w = hw % W; int h = hw / W;
    const bf16* ip = xw + (size_t)c * N;
    float s = 0.f;
    #pragma unroll
    for (int dh = -1; dh <= 1; dh++)
    #pragma unroll
    for (int dw = -1; dw <= 1; dw++)
    #pragma unroll
    for (int dt = -1; dt <= 1; dt++) {
        int hh = h + dh, ww = w + dw, tt = t + dt;
        bool ok = ((unsigned)hh < (unsigned)H) && ((unsigned)ww < (unsigned)W) && ((unsigned)tt < (unsigned)T);
        int off = ok ? ((hh * W + ww) * T + tt) : 0;
        s += ok ? b2f(ip[off]) : 0.f;
    }
    pm[idx] = f2b(s);
}

__global__ __launch_bounds__(256) void pf_kernel(const float* __restrict__ y, bf16* __restrict__ pf)
{
    int idx = blockIdx.x * 256 + threadIdx.x;
    if (idx >= 16 * NPF) return;
    int c = idx / NPF, r = idx % NPF;
    int d = r % PT; int ab = r / PT; int b = ab % PW; int a = ab / PW;
    const float* ip = y + (size_t)c * N;
    float s = 0.f;
    #pragma unroll
    for (int da = 0; da < 3; da++)
    #pragma unroll
    for (int db = 0; db < 3; db++)
    #pragma unroll
    for (int dd = 0; dd < 3; dd++) {
        int hh = a - 3 + da, ww = b - 3 + db, tt = d - 3 + dd;
        bool ok = ((unsigned)hh < (unsigned)H) && ((unsigned)ww < (unsigned)W) && ((unsigned)tt < (unsigned)T);
        int off = ok ? ((hh * W + ww) * T + tt) : 0;
        s += ok ? ip[off] : 0.f;
    }
    pf[idx] = f2b(s);
}

// corr -> corr_tmp[v][28] (ch-last chunk; idx 27 pad unused)
__global__ __launch_bounds__(256) void corr_kernel(const bf16* __restrict__ pm, const bf16* __restrict__ pf,
                                                   bf16* __restrict__ corr_tmp)
{
    int v = blockIdx.x * 256 + threadIdx.x;
    if (v >= N) return;
    int t = v % T; int hw = v / T; int w = hw % W; int h = hw / W;
    float pmv[16];
    #pragma unroll
    for (int c = 0; c < 16; c++) pmv[c] = b2f(pm[(size_t)c * N + v]);
    #pragma unroll 1
    for (int i = 0; i < 3; i++)
    #pragma unroll 1
    for (int j = 0; j < 3; j++)
    #pragma unroll 1
    for (int k = 0; k < 3; k++) {
        size_t base = ((size_t)(2 * i + h) * PW + (2 * j + w)) * PT + (2 * k + t);
        float s = 0.f;
        #pragma unroll
        for (int c = 0; c < 16; c++) s += pmv[c] * b2f(pf[(size_t)c * NPF + base]);
        corr_tmp[(size_t)v * 28 + (i * 9 + j * 3 + k)] = f2b(s * (1.f / 27.f));
    }
}

// assemble stack_cl[v][64]: ch0..15=xw, 16..42=corr, 43..58=y, 59..63=0
__global__ __launch_bounds__(256) void assemble_kernel(const bf16* __restrict__ xw,
                                                       const bf16* __restrict__ corr_tmp,
                                                       const float* __restrict__ y,
                                                       bf16* __restrict__ stack)
{
    int v = blockIdx.x * 256 + threadIdx.x;
    if (v >= N) return;
    unsigned short ch[64];
    #pragma unroll
    for (int c = 0; c < 16; c++) ch[c] = ((const unsigned short*)xw)[(size_t)c * N + v];
    #pragma unroll
    for (int i = 0; i < 27; i++) ch[16 + i] = ((const unsigned short*)corr_tmp)[(size_t)v * 28 + i];
    #pragma unroll
    for (int c = 0; c < 16; c++) { bf16 b = f2b(y[(size_t)c * N + v]); ch[43 + c] = *(unsigned short*)&b; }
    #pragma unroll
    for (int c = 59; c < 64; c++) ch[c] = 0;
    uint4* dst = (uint4*)((unsigned short*)stack + (size_t)v * 64);
    #pragma unroll
    for (int k = 0; k < 8; k++) dst[k] = ((uint4*)ch)[k];
}

// ================= MFMA implicit-GEMM conv =================
// in: channels-last [N][CST_IN] bf16. wb: frag-order (see wbuild). M-block = 128 voxels.
// 4 waves x 2 m-tiles; each wave: NT n-tiles of 16 couts.
// STORE: 0 = bf16 [N][CST_OUT] (all NT*16 ch); 1 = bf16 [N][16] nt0-only, no bias;
//        2 = like 0 but adds aux[v*16+n] to nt0 before ReLU; 3 = planar f32, ch<3 -> out.
template <int CST_IN, int KC, int KC_TOT, int NT, int NT_TOT, int CST_OUT, bool RELU, int STORE>
__global__ __launch_bounds__(256) void conv_mfma(const bf16* __restrict__ in,
                                                 const bf16* __restrict__ wb,
                                                 const float* __restrict__ bias,
                                                 const bf16* __restrict__ aux,
                                                 void* __restrict__ out,
                                                 const bf16* __restrict__ zp,
                                                 int kc_off, int nt_off)
{
    const int lane = threadIdx.x & 63;
    const int n16  = lane & 15;
    const int q    = lane >> 4;
    const int wv   = threadIdx.x >> 6;
    const int vbase = blockIdx.x * 128;

    int vox[2]; unsigned msk[2];
    #pragma unroll
    for (int m2 = 0; m2 < 2; ++m2) {
        int v = vbase + (wv * 2 + m2) * 16 + n16;
        vox[m2] = v;
        int t = v % T; int hw = v / T; int w = hw % W; int h = hw / W;
        bool vh[3] = { h > 0, true, h < H - 1 };
        bool vw[3] = { w > 0, true, w < W - 1 };
        bool vt[3] = { t > 0, true, t < T - 1 };
        unsigned m = 0;
        #pragma unroll
        for (int tap = 0; tap < 27; ++tap)
            if (vh[tap / 9] && vw[(tap % 9) / 3] && vt[tap % 3]) m |= (1u << tap);
        msk[m2] = m;
    }

    f32x4 acc[2][NT];
    #pragma unroll
    for (int nt = 0; nt < NT; ++nt) {
        float bv = (STORE == 1) ? 0.f : bias[nt * 16 + n16];
        #pragma unroll
        for (int m2 = 0; m2 < 2; ++m2)
            #pragma unroll
            for (int r = 0; r < 4; ++r) acc[m2][nt][r] = bv;
    }

    const int choff = q * 8;
    const short8* wb8 = (const short8*)wb;

    #pragma unroll 1
    for (int tap = 0; tap < 27; ++tap) {
        int dh = tap / 9, rr = tap - dh * 9, dw = rr / 3, dt = rr - dw * 3;
        int dof = (dh - 1) * WT + (dw - 1) * T + (dt - 1);
        const short* abase = (const short*)in + (ptrdiff_t)dof * CST_IN + choff;
        #pragma unroll
        for (int kc = 0; kc < KC; ++kc) {
            short8 av[2];
            #pragma unroll
            for (int m2 = 0; m2 < 2; ++m2) {
                bool ok = (msk[m2] >> tap) & 1u;
                const short* p = ok ? (abase + (ptrdiff_t)vox[m2] * CST_IN + kc * 32)
                                    : (const short*)zp;
                av[m2] = *(const short8*)p;
            }
            #pragma unroll
            for (int nt = 0; nt < NT; ++nt) {
                short8 bv8 = wb8[(size_t)(((tap * KC_TOT) + kc + kc_off) * NT_TOT + nt + nt_off) * 64 + lane];
                #pragma unroll
                for (int m2 = 0; m2 < 2; ++m2)
                    acc[m2][nt] = __builtin_amdgcn_mfma_f32_16x16x32_bf16(av[m2], bv8, acc[m2][nt], 0, 0, 0);
            }
        }
    }

    // store: C/D layout row = q*4+r, col = n16
    #pragma unroll
    for (int m2 = 0; m2 < 2; ++m2) {
        #pragma unroll
        for (int r = 0; r < 4; ++r) {
            int v = vbase + (wv * 2 + m2) * 16 + q * 4 + r;
            #pragma unroll
            for (int nt = 0; nt < NT; ++nt) {
                float x = acc[m2][nt][r];
                if (STORE == 2 && nt == 0) x += b2f(aux[(size_t)v * 16 + n16]);
                if (RELU) x = fmaxf(x, 0.f);
                if (STORE == 1) {
                    if (nt == 0) ((bf16*)out)[(size_t)v * 16 + n16] = f2b(x);
                } else if (STORE == 3) {
                    int ch = nt * 16 + n16;
                    if (ch < 3) ((float*)out)[(size_t)ch * N + v] = x;
                } else {
                    ((bf16*)out)[(size_t)v * CST_OUT + nt * 16 + n16] = f2b(x);
                }
            }
        }
    }
}

// sum = h + res, elementwise over [N][32]
__global__ __launch_bounds__(256) void add_kernel(const bf16* __restrict__ a, const bf16* __restrict__ b,
                                                  bf16* __restrict__ o)
{
    size_t i = (size_t)blockIdx.x * 256 + threadIdx.x;
    if (i < (size_t)N * 32) o[i] = f2b(b2f(a[i]) + b2f(b[i]));
}

extern "C" void kernel_launch(void* const* d_in, const int* in_sizes, int n_in,
                              void* d_out, int out_size, void* d_ws, size_t ws_size,
                              hipStream_t stream)
{
    (void)in_sizes; (void)n_in; (void)out_size; (void)ws_size;
    const float* x_p   = (const float*)d_in[0];
    const float* y_p   = (const float*)d_in[1];
    const float* flow_p= (const float*)d_in[2];
    const float* w1a_p = (const float*)d_in[3];
    const float* b1a_p = (const float*)d_in[4];
    const float* w1b_p = (const float*)d_in[5];
    const float* b1b_p = (const float*)d_in[6];
    const float* w2a_p = (const float*)d_in[7];
    const float* b2a_p = (const float*)d_in[8];
    const float* w2b_p = (const float*)d_in[9];
    const float* b2b_p = (const float*)d_in[10];
    const float* wf_p  = (const float*)d_in[11];
    const float* bf_p  = (const float*)d_in[12];

    // ---- workspace layout (bytes), peak 193.2 MB (< 203.6 proven safe) ----
    // A [0, 110,100,480): pf(31.2M)+pm(27.5M)+flow_up(10.3M) transients -> stack_cl[N][64]
    //                      -> (after conv1a-p2) h[N][32] @+0, t2/sum[N][32] @+55,050,240
    // B [110,100,480, +55,050,240): corr_tmp[N][28] -> buf1h[N][32] -> res[N][32]
    // C [165,150,720, +27,525,120): xw[16][N] -> hpart[N][16]
    // D [192,675,840, ...): wb1a|wb1b|wb2a|wb2b|wbf|biasp|zp  (~471 KB)
    char* wsb = (char*)d_ws;
    const size_t NB32 = (size_t)N * 32 * 2;      // 55,050,240
    const size_t A_off = 0, B_off = 2 * NB32, C_off = 3 * NB32;
    const size_t D_off = C_off + (size_t)N * 16 * 2;

    bf16*  pf       = (bf16*)(wsb + A_off);
    bf16*  pm       = (bf16*)(wsb + A_off + (size_t)16 * NPF * 2);
    float* flow_up  = (float*)(wsb + A_off + (size_t)16 * NPF * 2 + (size_t)16 * N * 2);
    bf16*  stack    = (bf16*)(wsb + A_off);                 // [N][64]
    bf16*  hbuf     = (bf16*)(wsb + A_off);                 // [N][32]
    bf16*  t2buf    = (bf16*)(wsb + A_off + NB32);          // [N][32]
    bf16*  sumbuf   = (bf16*)(wsb + A_off + NB32);          // [N][32] (t2 dead)
    bf16*  corr_tmp = (bf16*)(wsb + B_off);                 // [N][28]
    bf16*  buf1h    = (bf16*)(wsb + B_off);                 // [N][32]
    bf16*  resbuf   = (bf16*)(wsb + B_off);                 // [N][32]
    bf16*  xw       = (bf16*)(wsb + C_off);                 // [16][N]
    bf16*  hpart    = (bf16*)(wsb + C_off);                 // [N][16]
    bf16*  wb1a     = (bf16*)(wsb + D_off);                 // 27*2*4*512 = 110592
    bf16*  wb1b     = wb1a + 110592;                        // 27*2*2*512 = 55296
    bf16*  wb2a     = wb1b + 55296;                         // 27*1*2*512 = 27648
    bf16*  wb2b     = wb2a + 27648;
    bf16*  wbf      = wb2b + 27648;                         // 27*1*1*512 = 13824
    float* biasp    = (float*)(wbf + 13824);                // 176 f32
    bf16*  zp       = (bf16*)(biasp + 176);                 // 256 B zeros

    // weights / bias / zeropage
    wbuild_kernel<<<432, 256, 0, stream>>>(w1a_p, wb1a, 59, 59, 2, 4);
    wbuild_kernel<<<216, 256, 0, stream>>>(w1b_p, wb1b, 16, 59, 2, 2);
    wbuild_kernel<<<108, 256, 0, stream>>>(w2a_p, wb2a, 16, 16, 1, 2);
    wbuild_kernel<<<108, 256, 0, stream>>>(w2b_p, wb2b, 16, 16, 1, 2);
    wbuild_kernel<<<54,  256, 0, stream>>>(wf_p,  wbf,  3,  16, 1, 1);
    bias_kernel<<<1, 256, 0, stream>>>(b1a_p, b1b_p, b2a_p, b2b_p, bf_p, biasp);
    zp_kernel<<<1, 64, 0, stream>>>((unsigned*)zp);

    // pre-conv pipeline
    upsample_kernel<<<3 * N / 256, 256, 0, stream>>>(flow_p, flow_up);
    warp_kernel<<<N / 256, 256, 0, stream>>>(x_p, flow_up, xw);
    pm_kernel<<<16 * N / 256, 256, 0, stream>>>(xw, pm);
    pf_kernel<<<16 * NPF / 256, 256, 0, stream>>>(y_p, pf);
    corr_kernel<<<N / 256, 256, 0, stream>>>(pm, pf, corr_tmp);
    assemble_kernel<<<N / 256, 256, 0, stream>>>(xw, corr_tmp, y_p, stack);

    const int GB = N / 128;  // 6720 conv blocks
    // conv1a (59->59, CINP=64, COUTP=64) split over cout halves
    conv_mfma<64, 2, 2, 2, 4, 32, false, 0><<<GB, 256, 0, stream>>>(stack, wb1a, biasp + 0,  nullptr, buf1h, zp, 0, 0);
    // conv1b pass0: cin 0..31, partial (no bias/relu) -> hpart
    conv_mfma<32, 1, 2, 2, 2, 32, false, 1><<<GB, 256, 0, stream>>>(buf1h, wb1b, biasp,      nullptr, hpart, zp, 0, 0);
    // conv1a second cout half
    conv_mfma<64, 2, 2, 2, 4, 32, false, 0><<<GB, 256, 0, stream>>>(stack, wb1a, biasp + 32, nullptr, buf1h, zp, 0, 2);
    // conv1b pass1: cin 32..63, + hpart + bias, ReLU -> h [N][32]
    conv_mfma<32, 1, 2, 2, 2, 32, true,  2><<<GB, 256, 0, stream>>>(buf1h, wb1b, biasp + 64, hpart,   hbuf,  zp, 1, 0);
    // conv2a (16->16, pads zero)
    conv_mfma<32, 1, 1, 2, 2, 32, false, 0><<<GB, 256, 0, stream>>>(hbuf,  wb2a, biasp + 96, nullptr, t2buf, zp, 0, 0);
    // conv2b + ReLU -> res
    conv_mfma<32, 1, 1, 2, 2, 32, true,  0><<<GB, 256, 0, stream>>>(t2buf, wb2b, biasp + 128, nullptr, resbuf, zp, 0, 0);
    // sum = h + res
    add_kernel<<<(int)(((size_t)N * 32 + 255) / 256), 256, 0, stream>>>(hbuf, resbuf, sumbuf);
    // convf (16->3) -> planar f32 d_out
    conv_mfma<32, 1, 1, 1, 1, 16, false, 3><<<GB, 256, 0, stream>>>(sumbuf, wbf, biasp + 160, nullptr, d_out, zp, 0, 0);
}

// Round 5
// 2098.350 us; speedup vs baseline: 8.8476x; 1.1539x over previous
//
#include <hip/hip_runtime.h>
#include <hip/hip_bf16.h>
#include <cstddef>

typedef __hip_bfloat16 bf16;
typedef __attribute__((ext_vector_type(8))) short short8;   // 8 bf16 = one MFMA A/B frag
typedef __attribute__((ext_vector_type(4))) float f32x4;    // MFMA 16x16 accumulator

constexpr int H = 80, W = 96, T = 112;
constexpr int N = H * W * T;               // 860160
constexpr int WT = W * T;                  // 10752
constexpr int Hh = 40, Wh = 48, Th = 56;
constexpr int Nh = Hh * Wh * Th;
constexpr int PH = 84, PW = 100, PT = 116;
constexpr int NPF = PH * PW * PT;          // 974400

static __device__ __forceinline__ float b2f(bf16 v) { return __bfloat162float(v); }
static __device__ __forceinline__ bf16  f2b(float v) { return __float2bfloat16(v); }

// ================= weight build: w[COUT][CIN][27] f32 -> frag-order bf16 =================
// wb[((tap*KC_TOT+kc)*NT_TOT+nt)*64 + lane][j] = w[o=nt*16+(lane&15)][cin=kc*32+(lane>>4)*8+j][tap]
__global__ __launch_bounds__(256) void wbuild_kernel(const float* __restrict__ w, bf16* __restrict__ wb,
                                                     int COUT, int CIN, int KC_TOT, int NT_TOT)
{
    int idx = blockIdx.x * 256 + threadIdx.x;
    int total = 27 * KC_TOT * NT_TOT * 512;
    if (idx >= total) return;
    int j    = idx & 7;
    int lane = (idx >> 3) & 63;
    int rest = idx >> 9;
    int nt   = rest % NT_TOT; rest /= NT_TOT;
    int kc   = rest % KC_TOT;
    int tap  = rest / KC_TOT;
    int o    = nt * 16 + (lane & 15);
    int cin  = kc * 32 + (lane >> 4) * 8 + j;
    float val = (o < COUT && cin < CIN) ? w[((size_t)o * CIN + cin) * 27 + tap] : 0.f;
    wb[idx] = f2b(val);
}

// ---- padded biases: [0,64) b1a | [64,96) b1b | [96,128) b2a | [128,160) b2b | [160,176) bf
__global__ __launch_bounds__(256) void bias_kernel(const float* __restrict__ b1a, const float* __restrict__ b1b,
                                                   const float* __restrict__ b2a, const float* __restrict__ b2b,
                                                   const float* __restrict__ bff, float* __restrict__ out)
{
    int i = threadIdx.x;
    if (i < 64)       out[i] = (i < 59) ? b1a[i] : 0.f;
    else if (i < 96)  { int j = i - 64;  out[i] = (j < 16) ? b1b[j] : 0.f; }
    else if (i < 128) { int j = i - 96;  out[i] = (j < 16) ? b2a[j] : 0.f; }
    else if (i < 160) { int j = i - 128; out[i] = (j < 16) ? b2b[j] : 0.f; }
    else if (i < 176) { int j = i - 160; out[i] = (j < 3)  ? bff[j] : 0.f; }
}

__global__ __launch_bounds__(64) void zp_kernel(unsigned* __restrict__ zp)
{
    zp[threadIdx.x] = 0u;   // 256 B of zeros
}

// ================= pre-conv pipeline =================
__global__ __launch_bounds__(256) void upsample_kernel(const float* __restrict__ flow,
                                                       float* __restrict__ flow_up)
{
    int idx = blockIdx.x * 256 + threadIdx.x;
    if (idx >= 3 * N) return;
    int c = idx / N, v = idx % N;
    int t = v % T; int hw = v / T; int w = hw % W; int h = hw / W;
    float ph = (float)h * ((float)(Hh - 1) / (float)(H - 1));
    float pw = (float)w * ((float)(Wh - 1) / (float)(W - 1));
    float pt = (float)t * ((float)(Th - 1) / (float)(T - 1));
    int i0 = min((int)ph, Hh - 2); float fh = ph - (float)i0;
    int j0 = min((int)pw, Wh - 2); float fw = pw - (float)j0;
    int k0 = min((int)pt, Th - 2); float ft = pt - (float)k0;
    const float* fp = flow + (size_t)c * Nh;
    auto L = [&](int a, int b, int d) -> float {
        return 2.0f * fp[((size_t)a * Wh + b) * Th + d];
    };
    float v000 = L(i0, j0, k0),     v001 = L(i0, j0, k0 + 1);
    float v010 = L(i0, j0 + 1, k0), v011 = L(i0, j0 + 1, k0 + 1);
    float v100 = L(i0 + 1, j0, k0),     v101 = L(i0 + 1, j0, k0 + 1);
    float v110 = L(i0 + 1, j0 + 1, k0), v111 = L(i0 + 1, j0 + 1, k0 + 1);
    float val = (1.f - fh) * ((1.f - fw) * ((1.f - ft) * v000 + ft * v001)
                            +        fw  * ((1.f - ft) * v010 + ft * v011))
              +        fh  * ((1.f - fw) * ((1.f - ft) * v100 + ft * v101)
                            +        fw  * ((1.f - ft) * v110 + ft * v111));
    flow_up[idx] = val;
}

// warp -> xw planar bf16 [16][N]
__global__ __launch_bounds__(256) void warp_kernel(const float* __restrict__ x,
                                                   const float* __restrict__ flow_up,
                                                   bf16* __restrict__ xw)
{
    int v = blockIdx.x * 256 + threadIdx.x;
    if (v >= N) return;
    int t = v % T; int hw = v / T; int w = hw % W; int h = hw / W;
    float cx = (float)h + flow_up[v];
    float cy = (float)w + flow_up[N + v];
    float cz = (float)t + flow_up[2 * N + v];
    float fx0 = floorf(cx), fy0 = floorf(cy), fz0 = floorf(cz);
    float fx = cx - fx0, fy = cy - fy0, fz = cz - fz0;
    int ix = (int)fx0, iy = (int)fy0, iz = (int)fz0;

    float wc[8];
    int   oc[8];
    #pragma unroll
    for (int c8 = 0; c8 < 8; c8++) {
        int dx = (c8 >> 2) & 1, dy = (c8 >> 1) & 1, dz = c8 & 1;
        int ax = ix + dx, ay = iy + dy, az = iz + dz;
        bool ok = ((unsigned)ax < (unsigned)H) && ((unsigned)ay < (unsigned)W) && ((unsigned)az < (unsigned)T);
        float wt = (dx ? fx : 1.f - fx) * (dy ? fy : 1.f - fy) * (dz ? fz : 1.f - fz);
        wc[c8] = ok ? wt : 0.f;
        int cax = min(max(ax, 0), H - 1);
        int cay = min(max(ay, 0), W - 1);
        int caz = min(max(az, 0), T - 1);
        oc[c8] = (cax * W + cay) * T + caz;
    }
    #pragma unroll 1
    for (int c = 0; c < 16; c++) {
        const float* xp = x + (size_t)c * N;
        float s = 0.f;
        #pragma unroll
        for (int c8 = 0; c8 < 8; c8++) s += wc[c8] * xp[oc[c8]];
        xw[(size_t)c * N + v] = f2b(s);
    }
}

__global__ __launch_bounds__(256) void pm_kernel(const bf16* __restrict__ xw, bf16* __restrict__ pm)
{
    int idx = blockIdx.x * 256 + threadIdx.x;
    if (idx >= 16 * N) return;
    int c = idx / N, v = idx % N;
    int t = v % T; int hw = v / T; int w = hw % W; int h = hw / W;
    const bf16* ip = xw + (size_t)c * N;
    float s = 0.f;
    #pragma unroll
    for (int dh = -1; dh <= 1; dh++)
    #pragma unroll
    for (int dw = -1; dw <= 1; dw++)
    #pragma unroll
    for (int dt = -1; dt <= 1; dt++) {
        int hh = h + dh, ww = w + dw, tt = t + dt;
        bool ok = ((unsigned)hh < (unsigned)H) && ((unsigned)ww < (unsigned)W) && ((unsigned)tt < (unsigned)T);
        int off = ok ? ((hh * W + ww) * T + tt) : 0;
        s += ok ? b2f(ip[off]) : 0.f;
    }
    pm[idx] = f2b(s);
}

__global__ __launch_bounds__(256) void pf_kernel(const float* __restrict__ y, bf16* __restrict__ pf)
{
    int idx = blockIdx.x * 256 + threadIdx.x;
    if (idx >= 16 * NPF) return;
    int c = idx / NPF, r = idx % NPF;
    int d = r % PT; int ab = r / PT; int b = ab % PW; int a = ab / PW;
    const float* ip = y + (size_t)c * N;
    float s = 0.f;
    #pragma unroll
    for (int da = 0; da < 3; da++)
    #pragma unroll
    for (int db = 0; db < 3; db++)
    #pragma unroll
    for (int dd = 0; dd < 3; dd++) {
        int hh = a - 3 + da, ww = b - 3 + db, tt = d - 3 + dd;
        bool ok = ((unsigned)hh < (unsigned)H) && ((unsigned)ww < (unsigned)W) && ((unsigned)tt < (unsigned)T);
        int off = ok ? ((hh * W + ww) * T + tt) : 0;
        s += ok ? ip[off] : 0.f;
    }
    pf[idx] = f2b(s);
}

// corr -> corr_tmp[v][28]
__global__ __launch_bounds__(256) void corr_kernel(const bf16* __restrict__ pm, const bf16* __restrict__ pf,
                                                   bf16* __restrict__ corr_tmp)
{
    int v = blockIdx.x * 256 + threadIdx.x;
    if (v >= N) return;
    int t = v % T; int hw = v / T; int w = hw % W; int h = hw / W;
    float pmv[16];
    #pragma unroll
    for (int c = 0; c < 16; c++) pmv[c] = b2f(pm[(size_t)c * N + v]);
    #pragma unroll 1
    for (int i = 0; i < 3; i++)
    #pragma unroll 1
    for (int j = 0; j < 3; j++)
    #pragma unroll 1
    for (int k = 0; k < 3; k++) {
        size_t base = ((size_t)(2 * i + h) * PW + (2 * j + w)) * PT + (2 * k + t);
        float s = 0.f;
        #pragma unroll
        for (int c = 0; c < 16; c++) s += pmv[c] * b2f(pf[(size_t)c * NPF + base]);
        corr_tmp[(size_t)v * 28 + (i * 9 + j * 3 + k)] = f2b(s * (1.f / 27.f));
    }
}

// assemble stack_cl[v][64]: ch0..15=xw, 16..42=corr, 43..58=y, 59..63=0
__global__ __launch_bounds__(256) void assemble_kernel(const bf16* __restrict__ xw,
                                                       const bf16* __restrict__ corr_tmp,
                                                       const float* __restrict__ y,
                                                       bf16* __restrict__ stack)
{
    int v = blockIdx.x * 256 + threadIdx.x;
    if (v >= N) return;
    unsigned short ch[64];
    #pragma unroll
    for (int c = 0; c < 16; c++) ch[c] = ((const unsigned short*)xw)[(size_t)c * N + v];
    #pragma unroll
    for (int i = 0; i < 27; i++) ch[16 + i] = ((const unsigned short*)corr_tmp)[(size_t)v * 28 + i];
    #pragma unroll
    for (int c = 0; c < 16; c++) { bf16 b = f2b(y[(size_t)c * N + v]); ch[43 + c] = *(unsigned short*)&b; }
    #pragma unroll
    for (int c = 59; c < 64; c++) ch[c] = 0;
    uint4* dst = (uint4*)((unsigned short*)stack + (size_t)v * 64);
    #pragma unroll
    for (int k = 0; k < 8; k++) dst[k] = ((uint4*)ch)[k];
}

// ================= MFMA implicit-GEMM conv, 3-D brick blocks =================
// Block = 4h x 4w x 16t = 256 voxels; wave wv owns h-row h0+wv, MT=4 m-tiles (m2 = w offset),
// each m-tile = 16 t-consecutive voxels. Grid = 3360, XCD-chunked remap.
// STORE: 0 = bf16 [N][CST_OUT]; 1 = bf16 [N][16] nt0-only, no bias;
//        2 = 0 + aux[v*16+n] added to nt0 BEFORE relu; 3 = planar f32 ch<3 -> out;
//        4 = relu(x) + aux[v*CST_OUT+ch] (residual-add epilogue; RELU flag ignored).
template <int CST_IN, int KC, int KC_TOT, int NT, int NT_TOT, int CST_OUT, bool RELU, int STORE>
__global__ __launch_bounds__(256) void conv_mfma(const bf16* __restrict__ in,
                                                 const bf16* __restrict__ wb,
                                                 const float* __restrict__ bias,
                                                 const bf16* __restrict__ aux,
                                                 void* __restrict__ out,
                                                 const bf16* __restrict__ zp,
                                                 int kc_off, int nt_off)
{
    const int lane = threadIdx.x & 63;
    const int n16  = lane & 15;
    const int q    = lane >> 4;
    const int wv   = threadIdx.x >> 6;

    // XCD-chunked remap: blocks with same (bid&7) sweep a contiguous t-fastest range
    int bid = blockIdx.x;
    int cid = (bid & 7) * 420 + (bid >> 3);
    int t0  = (cid % 7) * 16;
    int rs  = cid / 7;
    int w0  = (rs % 24) * 4;
    int h0  = (rs / 24) * 4;
    const int h = h0 + wv;

    int vox[4]; unsigned msk[4];
    #pragma unroll
    for (int m2 = 0; m2 < 4; ++m2) {
        int w = w0 + m2, t = t0 + n16;
        vox[m2] = (h * W + w) * T + t;
        bool vh[3] = { h > 0, true, h < H - 1 };
        bool vw[3] = { w > 0, true, w < W - 1 };
        bool vt[3] = { t > 0, true, t < T - 1 };
        unsigned m = 0;
        #pragma unroll
        for (int tap = 0; tap < 27; ++tap)
            if (vh[tap / 9] && vw[(tap % 9) / 3] && vt[tap % 3]) m |= (1u << tap);
        msk[m2] = m;
    }

    f32x4 acc[4][NT];
    #pragma unroll
    for (int nt = 0; nt < NT; ++nt) {
        float bv = (STORE == 1) ? 0.f : bias[nt * 16 + n16];
        #pragma unroll
        for (int m2 = 0; m2 < 4; ++m2)
            #pragma unroll
            for (int r = 0; r < 4; ++r) acc[m2][nt][r] = bv;
    }

    const short* pA[4];
    #pragma unroll
    for (int m2 = 0; m2 < 4; ++m2)
        pA[m2] = (const short*)in + (size_t)vox[m2] * CST_IN + q * 8;
    const short8* wb8 = (const short8*)wb;

    #pragma unroll 1
    for (int tap = 0; tap < 27; ++tap) {
        int dh = tap / 9, rr = tap - dh * 9, dw = rr / 3, dt = rr - dw * 3;
        int dofCST = ((dh - 1) * WT + (dw - 1) * T + (dt - 1)) * CST_IN;

        short8 av[4][KC];
        #pragma unroll
        for (int m2 = 0; m2 < 4; ++m2) {
            bool ok = (msk[m2] >> tap) & 1u;
            #pragma unroll
            for (int kc = 0; kc < KC; ++kc) {
                const short* p = ok ? (pA[m2] + dofCST + kc * 32) : (const short*)zp;
                av[m2][kc] = *(const short8*)p;
            }
        }
        short8 bv8[KC][NT];
        #pragma unroll
        for (int kc = 0; kc < KC; ++kc)
            #pragma unroll
            for (int nt = 0; nt < NT; ++nt)
                bv8[kc][nt] = wb8[(size_t)(((tap * KC_TOT) + kc + kc_off) * NT_TOT + nt + nt_off) * 64 + lane];

        #pragma unroll
        for (int kc = 0; kc < KC; ++kc)
            #pragma unroll
            for (int nt = 0; nt < NT; ++nt)
                #pragma unroll
                for (int m2 = 0; m2 < 4; ++m2)
                    acc[m2][nt] = __builtin_amdgcn_mfma_f32_16x16x32_bf16(av[m2][kc], bv8[kc][nt], acc[m2][nt], 0, 0, 0);
    }

    // store: C/D layout row = q*4+r, col = n16
    #pragma unroll
    for (int m2 = 0; m2 < 4; ++m2) {
        int vrow = (h * W + (w0 + m2)) * T + t0 + q * 4;
        #pragma unroll
        for (int r = 0; r < 4; ++r) {
            int v = vrow + r;
            #pragma unroll
            for (int nt = 0; nt < NT; ++nt) {
                float x = acc[m2][nt][r];
                if (STORE == 2 && nt == 0) x += b2f(aux[(size_t)v * 16 + n16]);
                if (RELU && STORE != 4) x = fmaxf(x, 0.f);
                if (STORE == 4) x = fmaxf(x, 0.f) + b2f(aux[(size_t)v * CST_OUT + nt * 16 + n16]);
                if (STORE == 1) {
                    if (nt == 0) ((bf16*)out)[(size_t)v * 16 + n16] = f2b(x);
                } else if (STORE == 3) {
                    int ch = nt * 16 + n16;
                    if (ch < 3) ((float*)out)[(size_t)ch * N + v] = x;
                } else {
                    ((bf16*)out)[(size_t)v * CST_OUT + nt * 16 + n16] = f2b(x);
                }
            }
        }
    }
}

extern "C" void kernel_launch(void* const* d_in, const int* in_sizes, int n_in,
                              void* d_out, int out_size, void* d_ws, size_t ws_size,
                              hipStream_t stream)
{
    (void)in_sizes; (void)n_in; (void)out_size;
    const float* x_p   = (const float*)d_in[0];
    const float* y_p   = (const float*)d_in[1];
    const float* flow_p= (const float*)d_in[2];
    const float* w1a_p = (const float*)d_in[3];
    const float* b1a_p = (const float*)d_in[4];
    const float* w1b_p = (const float*)d_in[5];
    const float* b1b_p = (const float*)d_in[6];
    const float* w2a_p = (const float*)d_in[7];
    const float* b2a_p = (const float*)d_in[8];
    const float* w2b_p = (const float*)d_in[9];
    const float* b2b_p = (const float*)d_in[10];
    const float* wf_p  = (const float*)d_in[11];
    const float* bf_p  = (const float*)d_in[12];

    char* wsb = (char*)d_ws;
    const size_t NB32 = (size_t)N * 32 * 2;          // 55,050,240
    const size_t NB64 = 2 * NB32;                    // 110,100,480
    const size_t WSUM = (110592 + 55296 + 27648 + 27648 + 13824); // wb elements total = 235,008
    const size_t NEED_BIG = 2 * NB64 + WSUM * 2 + 176 * 4 + 256;  // 220,671,936
    const bool BIG = (ws_size >= NEED_BIG);

    // Common pointer set, path-dependent placement.
    bf16 *stack, *buf1, *pm, *pf, *xw, *corr_tmp, *hbuf, *t2buf, *sumbuf, *hpart, *buf1h;
    float* flow_up; bf16* wroot;
    if (BIG) {
        // stack@0 [N][64] | buf1@NB64 [N][64] | weights@2*NB64
        // transients: pm@0, pf@+16N*2, flow_up after pf (inside stack);
        //             xw@buf1+0, corr_tmp@buf1+27.5M (inside buf1)
        stack    = (bf16*)wsb;
        buf1     = (bf16*)(wsb + NB64);
        pm       = (bf16*)wsb;
        pf       = (bf16*)(wsb + (size_t)16 * N * 2);
        flow_up  = (float*)(wsb + (size_t)16 * N * 2 + (size_t)16 * NPF * 2);
        xw       = (bf16*)(wsb + NB64);
        corr_tmp = (bf16*)(wsb + NB64 + (size_t)16 * N * 2);
        hbuf     = (bf16*)wsb;                        // [N][32], stack dead after conv1a
        t2buf    = (bf16*)(wsb + NB32);
        sumbuf   = (bf16*)(wsb + NB64);               // buf1 dead after conv1b
        hpart    = nullptr; buf1h = nullptr;
        wroot    = (bf16*)(wsb + 2 * NB64);
    } else {
        // proven round-4 layout (~193.2 MB)
        const size_t A_off = 0, B_off = 2 * NB32, C_off = 3 * NB32;
        const size_t D_off = C_off + (size_t)N * 16 * 2;
        pf       = (bf16*)(wsb + A_off);
        pm       = (bf16*)(wsb + A_off + (size_t)16 * NPF * 2);
        flow_up  = (float*)(wsb + A_off + (size_t)16 * NPF * 2 + (size_t)16 * N * 2);
        stack    = (bf16*)(wsb + A_off);              // [N][64]
        hbuf     = (bf16*)(wsb + A_off);              // [N][32]
        t2buf    = (bf16*)(wsb + A_off + NB32);
        corr_tmp = (bf16*)(wsb + B_off);
        buf1h    = (bf16*)(wsb + B_off);              // [N][32]
        sumbuf   = (bf16*)(wsb + B_off);              // res/sum region
        xw       = (bf16*)(wsb + C_off);
        hpart    = (bf16*)(wsb + C_off);              // [N][16]
        buf1     = nullptr;
        wroot    = (bf16*)(wsb + D_off);
    }
    bf16*  wb1a  = wroot;
    bf16*  wb1b  = wb1a + 110592;
    bf16*  wb2a  = wb1b + 55296;
    bf16*  wb2b  = wb2a + 27648;
    bf16*  wbf   = wb2b + 27648;
    float* biasp = (float*)(wbf + 13824);
    bf16*  zp    = (bf16*)(biasp + 176);

    // weights / bias / zeropage
    wbuild_kernel<<<432, 256, 0, stream>>>(w1a_p, wb1a, 59, 59, 2, 4);
    wbuild_kernel<<<216, 256, 0, stream>>>(w1b_p, wb1b, 16, 59, 2, 2);
    wbuild_kernel<<<108, 256, 0, stream>>>(w2a_p, wb2a, 16, 16, 1, 2);
    wbuild_kernel<<<108, 256, 0, stream>>>(w2b_p, wb2b, 16, 16, 1, 2);
    wbuild_kernel<<<54,  256, 0, stream>>>(wf_p,  wbf,  3,  16, 1, 1);
    bias_kernel<<<1, 256, 0, stream>>>(b1a_p, b1b_p, b2a_p, b2b_p, bf_p, biasp);
    zp_kernel<<<1, 64, 0, stream>>>((unsigned*)zp);

    // pre-conv pipeline
    upsample_kernel<<<3 * N / 256, 256, 0, stream>>>(flow_p, flow_up);
    warp_kernel<<<N / 256, 256, 0, stream>>>(x_p, flow_up, xw);
    pm_kernel<<<16 * N / 256, 256, 0, stream>>>(xw, pm);
    pf_kernel<<<16 * NPF / 256, 256, 0, stream>>>(y_p, pf);
    corr_kernel<<<N / 256, 256, 0, stream>>>(pm, pf, corr_tmp);
    assemble_kernel<<<N / 256, 256, 0, stream>>>(xw, corr_tmp, y_p, stack);

    const int GB = N / 256;  // 3360 brick blocks
    if (BIG) {
        // conv1a single pass: 64ch in -> 64 couts
        conv_mfma<64, 2, 2, 4, 4, 64, false, 0><<<GB, 256, 0, stream>>>(stack, wb1a, biasp + 0,   nullptr, buf1,   zp, 0, 0);
        // conv1b single pass: 64 -> 32 (ReLU)
        conv_mfma<64, 2, 2, 2, 2, 32, true,  0><<<GB, 256, 0, stream>>>(buf1,  wb1b, biasp + 64,  nullptr, hbuf,   zp, 0, 0);
    } else {
        conv_mfma<64, 2, 2, 2, 4, 32, false, 0><<<GB, 256, 0, stream>>>(stack, wb1a, biasp + 0,   nullptr, buf1h,  zp, 0, 0);
        conv_mfma<32, 1, 2, 2, 2, 32, false, 1><<<GB, 256, 0, stream>>>(buf1h, wb1b, biasp,       nullptr, hpart,  zp, 0, 0);
        conv_mfma<64, 2, 2, 2, 4, 32, false, 0><<<GB, 256, 0, stream>>>(stack, wb1a, biasp + 32,  nullptr, buf1h,  zp, 0, 2);
        conv_mfma<32, 1, 2, 2, 2, 32, true,  2><<<GB, 256, 0, stream>>>(buf1h, wb1b, biasp + 64,  hpart,   hbuf,   zp, 1, 0);
    }
    // conv2a (16->16)
    conv_mfma<32, 1, 1, 2, 2, 32, false, 0><<<GB, 256, 0, stream>>>(hbuf,  wb2a, biasp + 96,  nullptr, t2buf,  zp, 0, 0);
    // conv2b + fused (relu + h add) -> sum
    conv_mfma<32, 1, 1, 2, 2, 32, false, 4><<<GB, 256, 0, stream>>>(t2buf, wb2b, biasp + 128, hbuf,    sumbuf, zp, 0, 0);
    // convf (16->3) -> planar f32 d_out
    conv_mfma<32, 1, 1, 1, 1, 16, false, 3><<<GB, 256, 0, stream>>>(sumbuf, wbf, biasp + 160, nullptr, d_out,  zp, 0, 0);
}

// Round 6
// 2088.577 us; speedup vs baseline: 8.8890x; 1.0047x over previous
//
#include <hip/hip_runtime.h>
#include <hip/hip_bf16.h>
#include <cstddef>
#include <type_traits>

typedef __hip_bfloat16 bf16;
typedef __attribute__((ext_vector_type(8))) short short8;   // 8 bf16 = one MFMA A/B frag
typedef __attribute__((ext_vector_type(4))) float f32x4;    // MFMA 16x16 accumulator

constexpr int H = 80, W = 96, T = 112;
constexpr int N = H * W * T;               // 860160
constexpr int WT = W * T;                  // 10752
constexpr int Hh = 40, Wh = 48, Th = 56;
constexpr int Nh = Hh * Wh * Th;
constexpr int PH = 84, PW = 100, PT = 116;
constexpr int NPF = PH * PW * PT;          // 974400

static __device__ __forceinline__ float b2f(bf16 v) { return __bfloat162float(v); }
static __device__ __forceinline__ bf16  f2b(float v) { return __float2bfloat16(v); }

// ================= weight build: w[COUT][CIN][27] f32 -> frag-order bf16 =================
// wb[((tap*KC_TOT+kc)*NT_TOT+nt)*64 + lane][j] = w[o=nt*16+(lane&15)][cin=kc*32+(lane>>4)*8+j][tap]
__global__ __launch_bounds__(256) void wbuild_kernel(const float* __restrict__ w, bf16* __restrict__ wb,
                                                     int COUT, int CIN, int KC_TOT, int NT_TOT)
{
    int idx = blockIdx.x * 256 + threadIdx.x;
    int total = 27 * KC_TOT * NT_TOT * 512;
    if (idx >= total) return;
    int j    = idx & 7;
    int lane = (idx >> 3) & 63;
    int rest = idx >> 9;
    int nt   = rest % NT_TOT; rest /= NT_TOT;
    int kc   = rest % KC_TOT;
    int tap  = rest / KC_TOT;
    int o    = nt * 16 + (lane & 15);
    int cin  = kc * 32 + (lane >> 4) * 8 + j;
    float val = (o < COUT && cin < CIN) ? w[((size_t)o * CIN + cin) * 27 + tap] : 0.f;
    wb[idx] = f2b(val);
}

// ---- padded biases: [0,64) b1a | [64,96) b1b | [96,128) b2a | [128,160) b2b | [160,176) bf
__global__ __launch_bounds__(256) void bias_kernel(const float* __restrict__ b1a, const float* __restrict__ b1b,
                                                   const float* __restrict__ b2a, const float* __restrict__ b2b,
                                                   const float* __restrict__ bff, float* __restrict__ out)
{
    int i = threadIdx.x;
    if (i < 64)       out[i] = (i < 59) ? b1a[i] : 0.f;
    else if (i < 96)  { int j = i - 64;  out[i] = (j < 16) ? b1b[j] : 0.f; }
    else if (i < 128) { int j = i - 96;  out[i] = (j < 16) ? b2a[j] : 0.f; }
    else if (i < 160) { int j = i - 128; out[i] = (j < 16) ? b2b[j] : 0.f; }
    else if (i < 176) { int j = i - 160; out[i] = (j < 3)  ? bff[j] : 0.f; }
}

__global__ __launch_bounds__(64) void zp_kernel(unsigned* __restrict__ zp)
{
    zp[threadIdx.x] = 0u;   // 256 B of zeros
}

// ================= pre-conv pipeline =================
__global__ __launch_bounds__(256) void upsample_kernel(const float* __restrict__ flow,
                                                       float* __restrict__ flow_up)
{
    int idx = blockIdx.x * 256 + threadIdx.x;
    if (idx >= 3 * N) return;
    int c = idx / N, v = idx % N;
    int t = v % T; int hw = v / T; int w = hw % W; int h = hw / W;
    float ph = (float)h * ((float)(Hh - 1) / (float)(H - 1));
    float pw = (float)w * ((float)(Wh - 1) / (float)(W - 1));
    float pt = (float)t * ((float)(Th - 1) / (float)(T - 1));
    int i0 = min((int)ph, Hh - 2); float fh = ph - (float)i0;
    int j0 = min((int)pw, Wh - 2); float fw = pw - (float)j0;
    int k0 = min((int)pt, Th - 2); float ft = pt - (float)k0;
    const float* fp = flow + (size_t)c * Nh;
    auto L = [&](int a, int b, int d) -> float {
        return 2.0f * fp[((size_t)a * Wh + b) * Th + d];
    };
    float v000 = L(i0, j0, k0),     v001 = L(i0, j0, k0 + 1);
    float v010 = L(i0, j0 + 1, k0), v011 = L(i0, j0 + 1, k0 + 1);
    float v100 = L(i0 + 1, j0, k0),     v101 = L(i0 + 1, j0, k0 + 1);
    float v110 = L(i0 + 1, j0 + 1, k0), v111 = L(i0 + 1, j0 + 1, k0 + 1);
    float val = (1.f - fh) * ((1.f - fw) * ((1.f - ft) * v000 + ft * v001)
                            +        fw  * ((1.f - ft) * v010 + ft * v011))
              +        fh  * ((1.f - fw) * ((1.f - ft) * v100 + ft * v101)
                            +        fw  * ((1.f - ft) * v110 + ft * v111));
    flow_up[idx] = val;
}

// warp -> xw planar bf16 [16][N]
__global__ __launch_bounds__(256) void warp_kernel(const float* __restrict__ x,
                                                   const float* __restrict__ flow_up,
                                                   bf16* __restrict__ xw)
{
    int v = blockIdx.x * 256 + threadIdx.x;
    if (v >= N) return;
    int t = v % T; int hw = v / T; int w = hw % W; int h = hw / W;
    float cx = (float)h + flow_up[v];
    float cy = (float)w + flow_up[N + v];
    float cz = (float)t + flow_up[2 * N + v];
    float fx0 = floorf(cx), fy0 = floorf(cy), fz0 = floorf(cz);
    float fx = cx - fx0, fy = cy - fy0, fz = cz - fz0;
    int ix = (int)fx0, iy = (int)fy0, iz = (int)fz0;

    float wc[8];
    int   oc[8];
    #pragma unroll
    for (int c8 = 0; c8 < 8; c8++) {
        int dx = (c8 >> 2) & 1, dy = (c8 >> 1) & 1, dz = c8 & 1;
        int ax = ix + dx, ay = iy + dy, az = iz + dz;
        bool ok = ((unsigned)ax < (unsigned)H) && ((unsigned)ay < (unsigned)W) && ((unsigned)az < (unsigned)T);
        float wt = (dx ? fx : 1.f - fx) * (dy ? fy : 1.f - fy) * (dz ? fz : 1.f - fz);
        wc[c8] = ok ? wt : 0.f;
        int cax = min(max(ax, 0), H - 1);
        int cay = min(max(ay, 0), W - 1);
        int caz = min(max(az, 0), T - 1);
        oc[c8] = (cax * W + cay) * T + caz;
    }
    #pragma unroll 1
    for (int c = 0; c < 16; c++) {
        const float* xp = x + (size_t)c * N;
        float s = 0.f;
        #pragma unroll
        for (int c8 = 0; c8 < 8; c8++) s += wc[c8] * xp[oc[c8]];
        xw[(size_t)c * N + v] = f2b(s);
    }
}

__global__ __launch_bounds__(256) void pm_kernel(const bf16* __restrict__ xw, bf16* __restrict__ pm)
{
    int idx = blockIdx.x * 256 + threadIdx.x;
    if (idx >= 16 * N) return;
    int c = idx / N, v = idx % N;
    int t = v % T; int hw = v / T; int w = hw % W; int h = hw / W;
    const bf16* ip = xw + (size_t)c * N;
    float s = 0.f;
    #pragma unroll
    for (int dh = -1; dh <= 1; dh++)
    #pragma unroll
    for (int dw = -1; dw <= 1; dw++)
    #pragma unroll
    for (int dt = -1; dt <= 1; dt++) {
        int hh = h + dh, ww = w + dw, tt = t + dt;
        bool ok = ((unsigned)hh < (unsigned)H) && ((unsigned)ww < (unsigned)W) && ((unsigned)tt < (unsigned)T);
        int off = ok ? ((hh * W + ww) * T + tt) : 0;
        s += ok ? b2f(ip[off]) : 0.f;
    }
    pm[idx] = f2b(s);
}

__global__ __launch_bounds__(256) void pf_kernel(const float* __restrict__ y, bf16* __restrict__ pf)
{
    int idx = blockIdx.x * 256 + threadIdx.x;
    if (idx >= 16 * NPF) return;
    int c = idx / NPF, r = idx % NPF;
    int d = r % PT; int ab = r / PT; int b = ab % PW; int a = ab / PW;
    const float* ip = y + (size_t)c * N;
    float s = 0.f;
    #pragma unroll
    for (int da = 0; da < 3; da++)
    #pragma unroll
    for (int db = 0; db < 3; db++)
    #pragma unroll
    for (int dd = 0; dd < 3; dd++) {
        int hh = a - 3 + da, ww = b - 3 + db, tt = d - 3 + dd;
        bool ok = ((unsigned)hh < (unsigned)H) && ((unsigned)ww < (unsigned)W) && ((unsigned)tt < (unsigned)T);
        int off = ok ? ((hh * W + ww) * T + tt) : 0;
        s += ok ? ip[off] : 0.f;
    }
    pf[idx] = f2b(s);
}

// corr -> corr_tmp[v][28]
__global__ __launch_bounds__(256) void corr_kernel(const bf16* __restrict__ pm, const bf16* __restrict__ pf,
                                                   bf16* __restrict__ corr_tmp)
{
    int v = blockIdx.x * 256 + threadIdx.x;
    if (v >= N) return;
    int t = v % T; int hw = v / T; int w = hw % W; int h = hw / W;
    float pmv[16];
    #pragma unroll
    for (int c = 0; c < 16; c++) pmv[c] = b2f(pm[(size_t)c * N + v]);
    #pragma unroll 1
    for (int i = 0; i < 3; i++)
    #pragma unroll 1
    for (int j = 0; j < 3; j++)
    #pragma unroll 1
    for (int k = 0; k < 3; k++) {
        size_t base = ((size_t)(2 * i + h) * PW + (2 * j + w)) * PT + (2 * k + t);
        float s = 0.f;
        #pragma unroll
        for (int c = 0; c < 16; c++) s += pmv[c] * b2f(pf[(size_t)c * NPF + base]);
        corr_tmp[(size_t)v * 28 + (i * 9 + j * 3 + k)] = f2b(s * (1.f / 27.f));
    }
}

// assemble stack_cl[v][64]: ch0..15=xw, 16..42=corr, 43..58=y, 59..63=0
__global__ __launch_bounds__(256) void assemble_kernel(const bf16* __restrict__ xw,
                                                       const bf16* __restrict__ corr_tmp,
                                                       const float* __restrict__ y,
                                                       bf16* __restrict__ stack)
{
    int v = blockIdx.x * 256 + threadIdx.x;
    if (v >= N) return;
    unsigned short ch[64];
    #pragma unroll
    for (int c = 0; c < 16; c++) ch[c] = ((const unsigned short*)xw)[(size_t)c * N + v];
    #pragma unroll
    for (int i = 0; i < 27; i++) ch[16 + i] = ((const unsigned short*)corr_tmp)[(size_t)v * 28 + i];
    #pragma unroll
    for (int c = 0; c < 16; c++) { bf16 b = f2b(y[(size_t)c * N + v]); ch[43 + c] = *(unsigned short*)&b; }
    #pragma unroll
    for (int c = 59; c < 64; c++) ch[c] = 0;
    uint4* dst = (uint4*)((unsigned short*)stack + (size_t)v * 64);
    #pragma unroll
    for (int k = 0; k < 8; k++) dst[k] = ((uint4*)ch)[k];
}

// ================= MFMA implicit-GEMM conv, 3-D brick blocks, sw-pipelined =================
// Block = 4h x 4w x 16t = 256 voxels; wave wv owns h-row h0+wv, MT=4 m-tiles (m2 = w offset).
// Tap loop unrolled x2 with alternating register buffers: loads for tap i+1 issue before the
// MFMAs of tap i (partial-vmcnt overlap). Interior bricks (59%) skip all boundary masking.
// STORE: 0 = bf16 [N][CST_OUT]; 1 = bf16 [N][16] nt0-only, no bias;
//        2 = 0 + aux[v*16+n] added to nt0 BEFORE relu; 3 = planar f32 ch<3 -> out;
//        4 = relu(x) + aux[v*CST_OUT+ch] (residual-add epilogue; RELU flag ignored).
template <int CST_IN, int KC, int KC_TOT, int NT, int NT_TOT, int CST_OUT, bool RELU, int STORE>
__global__ __launch_bounds__(256, 2) void conv_mfma(const bf16* __restrict__ in,
                                                    const bf16* __restrict__ wb,
                                                    const float* __restrict__ bias,
                                                    const bf16* __restrict__ aux,
                                                    void* __restrict__ out,
                                                    const bf16* __restrict__ zp,
                                                    int kc_off, int nt_off)
{
    const int lane = threadIdx.x & 63;
    const int n16  = lane & 15;
    const int q    = lane >> 4;
    const int wv   = threadIdx.x >> 6;

    // XCD-chunked remap: blocks with same (bid&7) sweep a contiguous t-fastest range
    int bid = blockIdx.x;
    int cid = (bid & 7) * 420 + (bid >> 3);
    int t0  = (cid % 7) * 16;
    int rs  = cid / 7;
    int w0  = (rs % 24) * 4;
    int h0  = (rs / 24) * 4;
    const int h = h0 + wv;

    const bool interior = (h0 != 0) && (h0 != H - 4) && (w0 != 0) && (w0 != W - 4)
                       && (t0 != 0) && (t0 != T - 16);

    f32x4 acc[4][NT];
    #pragma unroll
    for (int nt = 0; nt < NT; ++nt) {
        float bv = (STORE == 1) ? 0.f : bias[nt * 16 + n16];
        #pragma unroll
        for (int m2 = 0; m2 < 4; ++m2)
            #pragma unroll
            for (int r = 0; r < 4; ++r) acc[m2][nt][r] = bv;
    }

    const short* pA[4];
    #pragma unroll
    for (int m2 = 0; m2 < 4; ++m2)
        pA[m2] = (const short*)in + (size_t)((h * W + (w0 + m2)) * T + t0 + n16) * CST_IN + q * 8;
    const short8* wb8 = (const short8*)wb;

    auto body = [&](auto chk_c) {
        constexpr bool CHK = decltype(chk_c)::value;
        unsigned msk[4];
        if (CHK) {
            #pragma unroll
            for (int m2 = 0; m2 < 4; ++m2) {
                int w = w0 + m2, t = t0 + n16;
                bool vh[3] = { h > 0, true, h < H - 1 };
                bool vw[3] = { w > 0, true, w < W - 1 };
                bool vt[3] = { t > 0, true, t < T - 1 };
                unsigned m = 0;
                #pragma unroll
                for (int tap = 0; tap < 27; ++tap)
                    if (vh[tap / 9] && vw[(tap % 9) / 3] && vt[tap % 3]) m |= (1u << tap);
                msk[m2] = m;
            }
        }

        short8 avA[4][KC], bvA[KC][NT];
        short8 avB[4][KC], bvB[KC][NT];

        auto loadtap = [&](int tap, short8 (&av)[4][KC], short8 (&bv)[KC][NT]) {
            int dh = tap / 9, rr = tap - dh * 9, dw = rr / 3, dt = rr - dw * 3;
            int dofCST = ((dh - 1) * WT + (dw - 1) * T + (dt - 1)) * CST_IN;
            #pragma unroll
            for (int m2 = 0; m2 < 4; ++m2) {
                if (CHK) {
                    bool ok = (msk[m2] >> tap) & 1u;
                    #pragma unroll
                    for (int kc = 0; kc < KC; ++kc) {
                        const short* p = ok ? (pA[m2] + dofCST + kc * 32) : (const short*)zp;
                        av[m2][kc] = *(const short8*)p;
                    }
                } else {
                    #pragma unroll
                    for (int kc = 0; kc < KC; ++kc)
                        av[m2][kc] = *(const short8*)(pA[m2] + dofCST + kc * 32);
                }
            }
            #pragma unroll
            for (int kc = 0; kc < KC; ++kc)
                #pragma unroll
                for (int nt = 0; nt < NT; ++nt)
                    bv[kc][nt] = wb8[(size_t)(((tap * KC_TOT) + kc + kc_off) * NT_TOT + nt + nt_off) * 64 + lane];
        };
        auto mfmatap = [&](short8 (&av)[4][KC], short8 (&bv)[KC][NT]) {
            #pragma unroll
            for (int kc = 0; kc < KC; ++kc)
                #pragma unroll
                for (int nt = 0; nt < NT; ++nt)
                    #pragma unroll
                    for (int m2 = 0; m2 < 4; ++m2)
                        acc[m2][nt] = __builtin_amdgcn_mfma_f32_16x16x32_bf16(av[m2][kc], bv[kc][nt], acc[m2][nt], 0, 0, 0);
        };

        loadtap(0, avA, bvA);
        #pragma unroll 1
        for (int tap = 0; tap < 26; tap += 2) {
            loadtap(tap + 1, avB, bvB);
            mfmatap(avA, bvA);
            loadtap(tap + 2, avA, bvA);   // tap+2 <= 26 always (tap <= 24)
            mfmatap(avB, bvB);
        }
        mfmatap(avA, bvA);                // tap 26
    };
    if (interior) body(std::integral_constant<bool, false>{});
    else          body(std::integral_constant<bool, true>{});

    // store: C/D layout row = q*4+r, col = n16
    #pragma unroll
    for (int m2 = 0; m2 < 4; ++m2) {
        int vrow = (h * W + (w0 + m2)) * T + t0 + q * 4;
        #pragma unroll
        for (int r = 0; r < 4; ++r) {
            int v = vrow + r;
            #pragma unroll
            for (int nt = 0; nt < NT; ++nt) {
                float x = acc[m2][nt][r];
                if (STORE == 2 && nt == 0) x += b2f(aux[(size_t)v * 16 + n16]);
                if (RELU && STORE != 4) x = fmaxf(x, 0.f);
                if (STORE == 4) x = fmaxf(x, 0.f) + b2f(aux[(size_t)v * CST_OUT + nt * 16 + n16]);
                if (STORE == 1) {
                    if (nt == 0) ((bf16*)out)[(size_t)v * 16 + n16] = f2b(x);
                } else if (STORE == 3) {
                    int ch = nt * 16 + n16;
                    if (ch < 3) ((float*)out)[(size_t)ch * N + v] = x;
                } else {
                    ((bf16*)out)[(size_t)v * CST_OUT + nt * 16 + n16] = f2b(x);
                }
            }
        }
    }
}

extern "C" void kernel_launch(void* const* d_in, const int* in_sizes, int n_in,
                              void* d_out, int out_size, void* d_ws, size_t ws_size,
                              hipStream_t stream)
{
    (void)in_sizes; (void)n_in; (void)out_size;
    const float* x_p   = (const float*)d_in[0];
    const float* y_p   = (const float*)d_in[1];
    const float* flow_p= (const float*)d_in[2];
    const float* w1a_p = (const float*)d_in[3];
    const float* b1a_p = (const float*)d_in[4];
    const float* w1b_p = (const float*)d_in[5];
    const float* b1b_p = (const float*)d_in[6];
    const float* w2a_p = (const float*)d_in[7];
    const float* b2a_p = (const float*)d_in[8];
    const float* w2b_p = (const float*)d_in[9];
    const float* b2b_p = (const float*)d_in[10];
    const float* wf_p  = (const float*)d_in[11];
    const float* bf_p  = (const float*)d_in[12];

    char* wsb = (char*)d_ws;
    const size_t NB32 = (size_t)N * 32 * 2;          // 55,050,240
    const size_t NB64 = 2 * NB32;                    // 110,100,480
    const size_t WSUM = (110592 + 55296 + 27648 + 27648 + 13824); // wb elements total = 235,008
    const size_t NEED_BIG = 2 * NB64 + WSUM * 2 + 176 * 4 + 256;  // 220,671,936
    const bool BIG = (ws_size >= NEED_BIG);

    // Common pointer set, path-dependent placement.
    bf16 *stack, *buf1, *pm, *pf, *xw, *corr_tmp, *hbuf, *t2buf, *sumbuf, *hpart, *buf1h;
    float* flow_up; bf16* wroot;
    if (BIG) {
        // stack@0 [N][64] | buf1@NB64 [N][64] | weights@2*NB64
        stack    = (bf16*)wsb;
        buf1     = (bf16*)(wsb + NB64);
        pm       = (bf16*)wsb;
        pf       = (bf16*)(wsb + (size_t)16 * N * 2);
        flow_up  = (float*)(wsb + (size_t)16 * N * 2 + (size_t)16 * NPF * 2);
        xw       = (bf16*)(wsb + NB64);
        corr_tmp = (bf16*)(wsb + NB64 + (size_t)16 * N * 2);
        hbuf     = (bf16*)wsb;                        // [N][32], stack dead after conv1a
        t2buf    = (bf16*)(wsb + NB32);
        sumbuf   = (bf16*)(wsb + NB64);               // buf1 dead after conv1b
        hpart    = nullptr; buf1h = nullptr;
        wroot    = (bf16*)(wsb + 2 * NB64);
    } else {
        // proven round-4 layout (~193.2 MB)
        const size_t A_off = 0, B_off = 2 * NB32, C_off = 3 * NB32;
        const size_t D_off = C_off + (size_t)N * 16 * 2;
        pf       = (bf16*)(wsb + A_off);
        pm       = (bf16*)(wsb + A_off + (size_t)16 * NPF * 2);
        flow_up  = (float*)(wsb + A_off + (size_t)16 * NPF * 2 + (size_t)16 * N * 2);
        stack    = (bf16*)(wsb + A_off);              // [N][64]
        hbuf     = (bf16*)(wsb + A_off);              // [N][32]
        t2buf    = (bf16*)(wsb + A_off + NB32);
        corr_tmp = (bf16*)(wsb + B_off);
        buf1h    = (bf16*)(wsb + B_off);              // [N][32]
        sumbuf   = (bf16*)(wsb + B_off);              // res/sum region
        xw       = (bf16*)(wsb + C_off);
        hpart    = (bf16*)(wsb + C_off);              // [N][16]
        buf1     = nullptr;
        wroot    = (bf16*)(wsb + D_off);
    }
    bf16*  wb1a  = wroot;
    bf16*  wb1b  = wb1a + 110592;
    bf16*  wb2a  = wb1b + 55296;
    bf16*  wb2b  = wb2a + 27648;
    bf16*  wbf   = wb2b + 27648;
    float* biasp = (float*)(wbf + 13824);
    bf16*  zp    = (bf16*)(biasp + 176);

    // weights / bias / zeropage
    wbuild_kernel<<<432, 256, 0, stream>>>(w1a_p, wb1a, 59, 59, 2, 4);
    wbuild_kernel<<<216, 256, 0, stream>>>(w1b_p, wb1b, 16, 59, 2, 2);
    wbuild_kernel<<<108, 256, 0, stream>>>(w2a_p, wb2a, 16, 16, 1, 2);
    wbuild_kernel<<<108, 256, 0, stream>>>(w2b_p, wb2b, 16, 16, 1, 2);
    wbuild_kernel<<<54,  256, 0, stream>>>(wf_p,  wbf,  3,  16, 1, 1);
    bias_kernel<<<1, 256, 0, stream>>>(b1a_p, b1b_p, b2a_p, b2b_p, bf_p, biasp);
    zp_kernel<<<1, 64, 0, stream>>>((unsigned*)zp);

    // pre-conv pipeline
    upsample_kernel<<<3 * N / 256, 256, 0, stream>>>(flow_p, flow_up);
    warp_kernel<<<N / 256, 256, 0, stream>>>(x_p, flow_up, xw);
    pm_kernel<<<16 * N / 256, 256, 0, stream>>>(xw, pm);
    pf_kernel<<<16 * NPF / 256, 256, 0, stream>>>(y_p, pf);
    corr_kernel<<<N / 256, 256, 0, stream>>>(pm, pf, corr_tmp);
    assemble_kernel<<<N / 256, 256, 0, stream>>>(xw, corr_tmp, y_p, stack);

    const int GB = N / 256;  // 3360 brick blocks
    if (BIG) {
        conv_mfma<64, 2, 2, 4, 4, 64, false, 0><<<GB, 256, 0, stream>>>(stack, wb1a, biasp + 0,   nullptr, buf1,   zp, 0, 0);
        conv_mfma<64, 2, 2, 2, 2, 32, true,  0><<<GB, 256, 0, stream>>>(buf1,  wb1b, biasp + 64,  nullptr, hbuf,   zp, 0, 0);
    } else {
        conv_mfma<64, 2, 2, 2, 4, 32, false, 0><<<GB, 256, 0, stream>>>(stack, wb1a, biasp + 0,   nullptr, buf1h,  zp, 0, 0);
        conv_mfma<32, 1, 2, 2, 2, 32, false, 1><<<GB, 256, 0, stream>>>(buf1h, wb1b, biasp,       nullptr, hpart,  zp, 0, 0);
        conv_mfma<64, 2, 2, 2, 4, 32, false, 0><<<GB, 256, 0, stream>>>(stack, wb1a, biasp + 32,  nullptr, buf1h,  zp, 0, 2);
        conv_mfma<32, 1, 2, 2, 2, 32, true,  2><<<GB, 256, 0, stream>>>(buf1h, wb1b, biasp + 64,  hpart,   hbuf,   zp, 1, 0);
    }
    // conv2a (16->16)
    conv_mfma<32, 1, 1, 2, 2, 32, false, 0><<<GB, 256, 0, stream>>>(hbuf,  wb2a, biasp + 96,  nullptr, t2buf,  zp, 0, 0);
    // conv2b + fused (relu + h add) -> sum
    conv_mfma<32, 1, 1, 2, 2, 32, false, 4><<<GB, 256, 0, stream>>>(t2buf, wb2b, biasp + 128, hbuf,    sumbuf, zp, 0, 0);
    // convf (16->3) -> planar f32 d_out
    conv_mfma<32, 1, 1, 1, 1, 16, false, 3><<<GB, 256, 0, stream>>>(sumbuf, wbf, biasp + 160, nullptr, d_out,  zp, 0, 0);
}

// Round 7
// 1438.212 us; speedup vs baseline: 12.9086x; 1.4522x over previous
//
#include <hip/hip_runtime.h>
#include <hip/hip_bf16.h>
#include <cstddef>

typedef __hip_bfloat16 bf16;
typedef __attribute__((ext_vector_type(8))) short short8;   // 8 bf16 = one MFMA A/B frag
typedef __attribute__((ext_vector_type(4))) float f32x4;    // MFMA 16x16 accumulator

constexpr int H = 80, W = 96, T = 112;
constexpr int N = H * W * T;               // 860160
constexpr int WT = W * T;                  // 10752
constexpr int Hh = 40, Wh = 48, Th = 56;
constexpr int Nh = Hh * Wh * Th;
constexpr int PH = 84, PW = 100, PT = 116;
constexpr int NPF = PH * PW * PT;          // 974400

static __device__ __forceinline__ float b2f(bf16 v) { return __bfloat162float(v); }
static __device__ __forceinline__ bf16  f2b(float v) { return __float2bfloat16(v); }

// ================= weight build: w[COUT][CIN][27] f32 -> frag-order bf16 =================
// wb[((tap*KC_TOT+kc)*NT_TOT+nt)*64 + lane][j] = w[o=nt*16+(lane&15)][cin=kc*32+(lane>>4)*8+j][tap]
__global__ __launch_bounds__(256) void wbuild_kernel(const float* __restrict__ w, bf16* __restrict__ wb,
                                                     int COUT, int CIN, int KC_TOT, int NT_TOT)
{
    int idx = blockIdx.x * 256 + threadIdx.x;
    int total = 27 * KC_TOT * NT_TOT * 512;
    if (idx >= total) return;
    int j    = idx & 7;
    int lane = (idx >> 3) & 63;
    int rest = idx >> 9;
    int nt   = rest % NT_TOT; rest /= NT_TOT;
    int kc   = rest % KC_TOT;
    int tap  = rest / KC_TOT;
    int o    = nt * 16 + (lane & 15);
    int cin  = kc * 32 + (lane >> 4) * 8 + j;
    float val = (o < COUT && cin < CIN) ? w[((size_t)o * CIN + cin) * 27 + tap] : 0.f;
    wb[idx] = f2b(val);
}

// ---- padded biases: [0,64) b1a | [64,96) b1b | [96,128) b2a | [128,160) b2b | [160,176) bf
__global__ __launch_bounds__(256) void bias_kernel(const float* __restrict__ b1a, const float* __restrict__ b1b,
                                                   const float* __restrict__ b2a, const float* __restrict__ b2b,
                                                   const float* __restrict__ bff, float* __restrict__ out)
{
    int i = threadIdx.x;
    if (i < 64)       out[i] = (i < 59) ? b1a[i] : 0.f;
    else if (i < 96)  { int j = i - 64;  out[i] = (j < 16) ? b1b[j] : 0.f; }
    else if (i < 128) { int j = i - 96;  out[i] = (j < 16) ? b2a[j] : 0.f; }
    else if (i < 160) { int j = i - 128; out[i] = (j < 16) ? b2b[j] : 0.f; }
    else if (i < 176) { int j = i - 160; out[i] = (j < 3)  ? bff[j] : 0.f; }
}

// ================= pre-conv pipeline =================
__global__ __launch_bounds__(256) void upsample_kernel(const float* __restrict__ flow,
                                                       float* __restrict__ flow_up)
{
    int idx = blockIdx.x * 256 + threadIdx.x;
    if (idx >= 3 * N) return;
    int c = idx / N, v = idx % N;
    int t = v % T; int hw = v / T; int w = hw % W; int h = hw / W;
    float ph = (float)h * ((float)(Hh - 1) / (float)(H - 1));
    float pw = (float)w * ((float)(Wh - 1) / (float)(W - 1));
    float pt = (float)t * ((float)(Th - 1) / (float)(T - 1));
    int i0 = min((int)ph, Hh - 2); float fh = ph - (float)i0;
    int j0 = min((int)pw, Wh - 2); float fw = pw - (float)j0;
    int k0 = min((int)pt, Th - 2); float ft = pt - (float)k0;
    const float* fp = flow + (size_t)c * Nh;
    auto L = [&](int a, int b, int d) -> float {
        return 2.0f * fp[((size_t)a * Wh + b) * Th + d];
    };
    float v000 = L(i0, j0, k0),     v001 = L(i0, j0, k0 + 1);
    float v010 = L(i0, j0 + 1, k0), v011 = L(i0, j0 + 1, k0 + 1);
    float v100 = L(i0 + 1, j0, k0),     v101 = L(i0 + 1, j0, k0 + 1);
    float v110 = L(i0 + 1, j0 + 1, k0), v111 = L(i0 + 1, j0 + 1, k0 + 1);
    float val = (1.f - fh) * ((1.f - fw) * ((1.f - ft) * v000 + ft * v001)
                            +        fw  * ((1.f - ft) * v010 + ft * v011))
              +        fh  * ((1.f - fw) * ((1.f - ft) * v100 + ft * v101)
                            +        fw  * ((1.f - ft) * v110 + ft * v111));
    flow_up[idx] = val;
}

// warp -> xw planar bf16 [16][N]
__global__ __launch_bounds__(256) void warp_kernel(const float* __restrict__ x,
                                                   const float* __restrict__ flow_up,
                                                   bf16* __restrict__ xw)
{
    int v = blockIdx.x * 256 + threadIdx.x;
    if (v >= N) return;
    int t = v % T; int hw = v / T; int w = hw % W; int h = hw / W;
    float cx = (float)h + flow_up[v];
    float cy = (float)w + flow_up[N + v];
    float cz = (float)t + flow_up[2 * N + v];
    float fx0 = floorf(cx), fy0 = floorf(cy), fz0 = floorf(cz);
    float fx = cx - fx0, fy = cy - fy0, fz = cz - fz0;
    int ix = (int)fx0, iy = (int)fy0, iz = (int)fz0;

    float wc[8];
    int   oc[8];
    #pragma unroll
    for (int c8 = 0; c8 < 8; c8++) {
        int dx = (c8 >> 2) & 1, dy = (c8 >> 1) & 1, dz = c8 & 1;
        int ax = ix + dx, ay = iy + dy, az = iz + dz;
        bool ok = ((unsigned)ax < (unsigned)H) && ((unsigned)ay < (unsigned)W) && ((unsigned)az < (unsigned)T);
        float wt = (dx ? fx : 1.f - fx) * (dy ? fy : 1.f - fy) * (dz ? fz : 1.f - fz);
        wc[c8] = ok ? wt : 0.f;
        int cax = min(max(ax, 0), H - 1);
        int cay = min(max(ay, 0), W - 1);
        int caz = min(max(az, 0), T - 1);
        oc[c8] = (cax * W + cay) * T + caz;
    }
    #pragma unroll 1
    for (int c = 0; c < 16; c++) {
        const float* xp = x + (size_t)c * N;
        float s = 0.f;
        #pragma unroll
        for (int c8 = 0; c8 < 8; c8++) s += wc[c8] * xp[oc[c8]];
        xw[(size_t)c * N + v] = f2b(s);
    }
}

__global__ __launch_bounds__(256) void pm_kernel(const bf16* __restrict__ xw, bf16* __restrict__ pm)
{
    int idx = blockIdx.x * 256 + threadIdx.x;
    if (idx >= 16 * N) return;
    int c = idx / N, v = idx % N;
    int t = v % T; int hw = v / T; int w = hw % W; int h = hw / W;
    const bf16* ip = xw + (size_t)c * N;
    float s = 0.f;
    #pragma unroll
    for (int dh = -1; dh <= 1; dh++)
    #pragma unroll
    for (int dw = -1; dw <= 1; dw++)
    #pragma unroll
    for (int dt = -1; dt <= 1; dt++) {
        int hh = h + dh, ww = w + dw, tt = t + dt;
        bool ok = ((unsigned)hh < (unsigned)H) && ((unsigned)ww < (unsigned)W) && ((unsigned)tt < (unsigned)T);
        int off = ok ? ((hh * W + ww) * T + tt) : 0;
        s += ok ? b2f(ip[off]) : 0.f;
    }
    pm[idx] = f2b(s);
}

__global__ __launch_bounds__(256) void pf_kernel(const float* __restrict__ y, bf16* __restrict__ pf)
{
    int idx = blockIdx.x * 256 + threadIdx.x;
    if (idx >= 16 * NPF) return;
    int c = idx / NPF, r = idx % NPF;
    int d = r % PT; int ab = r / PT; int b = ab % PW; int a = ab / PW;
    const float* ip = y + (size_t)c * N;
    float s = 0.f;
    #pragma unroll
    for (int da = 0; da < 3; da++)
    #pragma unroll
    for (int db = 0; db < 3; db++)
    #pragma unroll
    for (int dd = 0; dd < 3; dd++) {
        int hh = a - 3 + da, ww = b - 3 + db, tt = d - 3 + dd;
        bool ok = ((unsigned)hh < (unsigned)H) && ((unsigned)ww < (unsigned)W) && ((unsigned)tt < (unsigned)T);
        int off = ok ? ((hh * W + ww) * T + tt) : 0;
        s += ok ? ip[off] : 0.f;
    }
    pf[idx] = f2b(s);
}

// corr -> corr_tmp[v][28]
__global__ __launch_bounds__(256) void corr_kernel(const bf16* __restrict__ pm, const bf16* __restrict__ pf,
                                                   bf16* __restrict__ corr_tmp)
{
    int v = blockIdx.x * 256 + threadIdx.x;
    if (v >= N) return;
    int t = v % T; int hw = v / T; int w = hw % W; int h = hw / W;
    float pmv[16];
    #pragma unroll
    for (int c = 0; c < 16; c++) pmv[c] = b2f(pm[(size_t)c * N + v]);
    #pragma unroll 1
    for (int i = 0; i < 3; i++)
    #pragma unroll 1
    for (int j = 0; j < 3; j++)
    #pragma unroll 1
    for (int k = 0; k < 3; k++) {
        size_t base = ((size_t)(2 * i + h) * PW + (2 * j + w)) * PT + (2 * k + t);
        float s = 0.f;
        #pragma unroll
        for (int c = 0; c < 16; c++) s += pmv[c] * b2f(pf[(size_t)c * NPF + base]);
        corr_tmp[(size_t)v * 28 + (i * 9 + j * 3 + k)] = f2b(s * (1.f / 27.f));
    }
}

// assemble stack_cl[v][64]: ch0..15=xw, 16..42=corr, 43..58=y, 59..63=0
__global__ __launch_bounds__(256) void assemble_kernel(const bf16* __restrict__ xw,
                                                       const bf16* __restrict__ corr_tmp,
                                                       const float* __restrict__ y,
                                                       bf16* __restrict__ stack)
{
    int v = blockIdx.x * 256 + threadIdx.x;
    if (v >= N) return;
    unsigned short ch[64];
    #pragma unroll
    for (int c = 0; c < 16; c++) ch[c] = ((const unsigned short*)xw)[(size_t)c * N + v];
    #pragma unroll
    for (int i = 0; i < 27; i++) ch[16 + i] = ((const unsigned short*)corr_tmp)[(size_t)v * 28 + i];
    #pragma unroll
    for (int c = 0; c < 16; c++) { bf16 b = f2b(y[(size_t)c * N + v]); ch[43 + c] = *(unsigned short*)&b; }
    #pragma unroll
    for (int c = 59; c < 64; c++) ch[c] = 0;
    uint4* dst = (uint4*)((unsigned short*)stack + (size_t)v * 64);
    #pragma unroll
    for (int k = 0; k < 8; k++) dst[k] = ((uint4*)ch)[k];
}

// ================= MFMA implicit-GEMM conv with LDS A-halo =================
// Block = 4h x 4w x 16t brick (256 voxels), 4 waves; wave wv owns h-row h0+wv, 4 m-tiles (w cols).
// Per kc-pass (32 input ch): stage the 6x6x18 halo's 64B kc-slice into LDS (80B/slot: 2-way
// bank aliasing = free), then tap loop reads A via ds_read_b128 (boundary -> LDS zero slot)
// and B from global (frag-order, dbuf-prefetched). TA instrs per block drop ~4x vs r6.
// STORE: 0 = bf16 [N][CST_OUT]; 1 = bf16 [N][16] nt0-only, no bias;
//        2 = 0 + aux[v*16+n] added to nt0 BEFORE relu; 3 = planar f32 ch<3 -> out;
//        4 = relu(x) + aux[v*CST_OUT+ch] (residual-add epilogue; RELU flag ignored).
template <int CST_IN, int KC_TOT, int NT, int NT_TOT, int CST_OUT, bool RELU, int STORE>
__global__ __launch_bounds__(256, 3) void conv_lds(const bf16* __restrict__ in,
                                                   const bf16* __restrict__ wb,
                                                   const float* __restrict__ bias,
                                                   const bf16* __restrict__ aux,
                                                   void* __restrict__ out,
                                                   int kc_off, int nt_off)
{
    constexpr int KCP     = CST_IN / 32;   // internal kc passes
    constexpr int ASTRIDE = 80;            // 64B data + 16B pad per halo slot
    constexpr int ZOFF    = 648 * ASTRIDE; // zero slot
    __shared__ __align__(16) char smem[648 * ASTRIDE + 16];

    const int tid  = threadIdx.x;
    const int lane = tid & 63;
    const int n16  = lane & 15;
    const int q    = lane >> 4;
    const int wv   = tid >> 6;

    // XCD-chunked remap
    int bid = blockIdx.x;
    int cid = (bid & 7) * 420 + (bid >> 3);
    int t0  = (cid % 7) * 16;
    int rs  = cid / 7;
    int w0  = (rs % 24) * 4;
    int h0  = (rs / 24) * 4;
    const int h = h0 + wv;

    // 27-bit validity mask per m-tile
    unsigned msk[4];
    #pragma unroll
    for (int m2 = 0; m2 < 4; ++m2) {
        int w = w0 + m2, t = t0 + n16;
        bool vh[3] = { h > 0, true, h < H - 1 };
        bool vw[3] = { w > 0, true, w < W - 1 };
        bool vt[3] = { t > 0, true, t < T - 1 };
        unsigned m = 0;
        #pragma unroll
        for (int tap = 0; tap < 27; ++tap)
            if (vh[tap / 9] && vw[(tap % 9) / 3] && vt[tap % 3]) m |= (1u << tap);
        msk[m2] = m;
    }

    f32x4 acc[4][NT];
    #pragma unroll
    for (int nt = 0; nt < NT; ++nt) {
        float bv = (STORE == 1) ? 0.f : bias[nt * 16 + n16];
        #pragma unroll
        for (int m2 = 0; m2 < 4; ++m2)
            #pragma unroll
            for (int r = 0; r < 4; ++r) acc[m2][nt][r] = bv;
    }

    if (tid < 4) *(int*)(smem + ZOFF + tid * 4) = 0;   // zero slot (pre-first-barrier)

    #pragma unroll 1
    for (int kcp = 0; kcp < KCP; ++kcp) {
        if (kcp > 0) __syncthreads();   // all reads of previous A slice done
        // ---- stage A halo kc-slice: 648 slots x 64B, 4 lanes/slot ----
        #pragma unroll 1
        for (int it = 0; it < 11; ++it) {
            int slot = it * 64 + (tid >> 2);
            if (slot < 648) {
                int hh = slot / 108, rm = slot - hh * 108;
                int ww = rm / 18,    tt = rm - ww * 18;
                int gh = min(max(h0 - 1 + hh, 0), H - 1);
                int gw = min(max(w0 - 1 + ww, 0), W - 1);
                int gt = min(max(t0 - 1 + tt, 0), T - 1);
                const char* gp = (const char*)in + (size_t)((gh * W + gw) * T + gt) * (CST_IN * 2)
                                 + kcp * 64 + (tid & 3) * 16;
                *(uint4*)(smem + slot * ASTRIDE + (tid & 3) * 16) = *(const uint4*)gp;
            }
        }
        __syncthreads();

        auto loadB = [&](int tap, short8 (&bv)[NT]) {
            #pragma unroll
            for (int nt = 0; nt < NT; ++nt) {
                size_t grec = (size_t)((tap * KC_TOT) + kcp + kc_off) * NT_TOT + nt + nt_off;
                bv[nt] = *(const short8*)((const char*)wb + grec * 1024 + (size_t)lane * 16);
            }
        };
        auto tapcompute = [&](int tap, short8 (&bv)[NT]) {
            int dh = tap / 9, rr = tap - dh * 9, dw = rr / 3, dt = rr - dw * 3;
            short8 av[4];
            #pragma unroll
            for (int m2 = 0; m2 < 4; ++m2) {
                bool ok = (msk[m2] >> tap) & 1u;
                int hvox = ((wv + dh) * 6 + (m2 + dw)) * 18 + (n16 + dt);
                const char* p = ok ? (smem + hvox * ASTRIDE + q * 16) : (smem + ZOFF);
                av[m2] = *(const short8*)p;
            }
            #pragma unroll
            for (int nt = 0; nt < NT; ++nt)
                #pragma unroll
                for (int m2 = 0; m2 < 4; ++m2)
                    acc[m2][nt] = __builtin_amdgcn_mfma_f32_16x16x32_bf16(av[m2], bv[nt], acc[m2][nt], 0, 0, 0);
        };

        short8 bvA[NT], bvB[NT];
        loadB(0, bvA);
        #pragma unroll 1
        for (int tap = 0; tap < 26; tap += 2) {
            loadB(tap + 1, bvB);
            tapcompute(tap, bvA);
            loadB(tap + 2, bvA);
            tapcompute(tap + 1, bvB);
        }
        tapcompute(26, bvA);
    }

    // store: C/D layout row = q*4+r, col = n16
    #pragma unroll
    for (int m2 = 0; m2 < 4; ++m2) {
        int vrow = (h * W + (w0 + m2)) * T + t0 + q * 4;
        #pragma unroll
        for (int r = 0; r < 4; ++r) {
            int v = vrow + r;
            #pragma unroll
            for (int nt = 0; nt < NT; ++nt) {
                float x = acc[m2][nt][r];
                if (STORE == 2 && nt == 0) x += b2f(aux[(size_t)v * 16 + n16]);
                if (RELU && STORE != 4) x = fmaxf(x, 0.f);
                if (STORE == 4) x = fmaxf(x, 0.f) + b2f(aux[(size_t)v * CST_OUT + nt * 16 + n16]);
                if (STORE == 1) {
                    if (nt == 0) ((bf16*)out)[(size_t)v * 16 + n16] = f2b(x);
                } else if (STORE == 3) {
                    int ch = nt * 16 + n16;
                    if (ch < 3) ((float*)out)[(size_t)ch * N + v] = x;
                } else {
                    ((bf16*)out)[(size_t)v * CST_OUT + nt * 16 + n16] = f2b(x);
                }
            }
        }
    }
}

extern "C" void kernel_launch(void* const* d_in, const int* in_sizes, int n_in,
                              void* d_out, int out_size, void* d_ws, size_t ws_size,
                              hipStream_t stream)
{
    (void)in_sizes; (void)n_in; (void)out_size;
    const float* x_p   = (const float*)d_in[0];
    const float* y_p   = (const float*)d_in[1];
    const float* flow_p= (const float*)d_in[2];
    const float* w1a_p = (const float*)d_in[3];
    const float* b1a_p = (const float*)d_in[4];
    const float* w1b_p = (const float*)d_in[5];
    const float* b1b_p = (const float*)d_in[6];
    const float* w2a_p = (const float*)d_in[7];
    const float* b2a_p = (const float*)d_in[8];
    const float* w2b_p = (const float*)d_in[9];
    const float* b2b_p = (const float*)d_in[10];
    const float* wf_p  = (const float*)d_in[11];
    const float* bf_p  = (const float*)d_in[12];

    char* wsb = (char*)d_ws;
    const size_t NB32 = (size_t)N * 32 * 2;          // 55,050,240
    const size_t NB64 = 2 * NB32;                    // 110,100,480
    const size_t WSUM = (110592 + 55296 + 27648 + 27648 + 13824); // wb elements total
    const size_t NEED_BIG = 2 * NB64 + WSUM * 2 + 176 * 4 + 256;  // 220,671,936
    const bool BIG = (ws_size >= NEED_BIG);

    bf16 *stack, *buf1, *pm, *pf, *xw, *corr_tmp, *hbuf, *t2buf, *sumbuf, *hpart, *buf1h;
    float* flow_up; bf16* wroot;
    if (BIG) {
        stack    = (bf16*)wsb;
        buf1     = (bf16*)(wsb + NB64);
        pm       = (bf16*)wsb;
        pf       = (bf16*)(wsb + (size_t)16 * N * 2);
        flow_up  = (float*)(wsb + (size_t)16 * N * 2 + (size_t)16 * NPF * 2);
        xw       = (bf16*)(wsb + NB64);
        corr_tmp = (bf16*)(wsb + NB64 + (size_t)16 * N * 2);
        hbuf     = (bf16*)wsb;                        // [N][32], stack dead after conv1a
        t2buf    = (bf16*)(wsb + NB32);
        sumbuf   = (bf16*)(wsb + NB64);               // buf1 dead after conv1b
        hpart    = nullptr; buf1h = nullptr;
        wroot    = (bf16*)(wsb + 2 * NB64);
    } else {
        const size_t A_off = 0, B_off = 2 * NB32, C_off = 3 * NB32;
        const size_t D_off = C_off + (size_t)N * 16 * 2;
        pf       = (bf16*)(wsb + A_off);
        pm       = (bf16*)(wsb + A_off + (size_t)16 * NPF * 2);
        flow_up  = (float*)(wsb + A_off + (size_t)16 * NPF * 2 + (size_t)16 * N * 2);
        stack    = (bf16*)(wsb + A_off);
        hbuf     = (bf16*)(wsb + A_off);
        t2buf    = (bf16*)(wsb + A_off + NB32);
        corr_tmp = (bf16*)(wsb + B_off);
        buf1h    = (bf16*)(wsb + B_off);
        sumbuf   = (bf16*)(wsb + B_off);
        xw       = (bf16*)(wsb + C_off);
        hpart    = (bf16*)(wsb + C_off);
        buf1     = nullptr;
        wroot    = (bf16*)(wsb + D_off);
    }
    bf16*  wb1a  = wroot;
    bf16*  wb1b  = wb1a + 110592;
    bf16*  wb2a  = wb1b + 55296;
    bf16*  wb2b  = wb2a + 27648;
    bf16*  wbf   = wb2b + 27648;
    float* biasp = (float*)(wbf + 13824);

    wbuild_kernel<<<432, 256, 0, stream>>>(w1a_p, wb1a, 59, 59, 2, 4);
    wbuild_kernel<<<216, 256, 0, stream>>>(w1b_p, wb1b, 16, 59, 2, 2);
    wbuild_kernel<<<108, 256, 0, stream>>>(w2a_p, wb2a, 16, 16, 1, 2);
    wbuild_kernel<<<108, 256, 0, stream>>>(w2b_p, wb2b, 16, 16, 1, 2);
    wbuild_kernel<<<54,  256, 0, stream>>>(wf_p,  wbf,  3,  16, 1, 1);
    bias_kernel<<<1, 256, 0, stream>>>(b1a_p, b1b_p, b2a_p, b2b_p, bf_p, biasp);

    upsample_kernel<<<3 * N / 256, 256, 0, stream>>>(flow_p, flow_up);
    warp_kernel<<<N / 256, 256, 0, stream>>>(x_p, flow_up, xw);
    pm_kernel<<<16 * N / 256, 256, 0, stream>>>(xw, pm);
    pf_kernel<<<16 * NPF / 256, 256, 0, stream>>>(y_p, pf);
    corr_kernel<<<N / 256, 256, 0, stream>>>(pm, pf, corr_tmp);
    assemble_kernel<<<N / 256, 256, 0, stream>>>(xw, corr_tmp, y_p, stack);

    const int GB = N / 256;  // 3360 brick blocks
    if (BIG) {
        conv_lds<64, 2, 4, 4, 64, false, 0><<<GB, 256, 0, stream>>>(stack, wb1a, biasp + 0,   nullptr, buf1,  0, 0);
        conv_lds<64, 2, 2, 2, 32, true,  0><<<GB, 256, 0, stream>>>(buf1,  wb1b, biasp + 64,  nullptr, hbuf,  0, 0);
    } else {
        conv_lds<64, 2, 2, 4, 32, false, 0><<<GB, 256, 0, stream>>>(stack, wb1a, biasp + 0,   nullptr, buf1h, 0, 0);
        conv_lds<32, 2, 2, 2, 32, false, 1><<<GB, 256, 0, stream>>>(buf1h, wb1b, biasp,       nullptr, hpart, 0, 0);
        conv_lds<64, 2, 2, 4, 32, false, 0><<<GB, 256, 0, stream>>>(stack, wb1a, biasp + 32,  nullptr, buf1h, 0, 2);
        conv_lds<32, 2, 2, 2, 32, true,  2><<<GB, 256, 0, stream>>>(buf1h, wb1b, biasp + 64,  hpart,   hbuf,  1, 0);
    }
    conv_lds<32, 1, 2, 2, 32, false, 0><<<GB, 256, 0, stream>>>(hbuf,  wb2a, biasp + 96,  nullptr, t2buf,  0, 0);
    conv_lds<32, 1, 2, 2, 32, false, 4><<<GB, 256, 0, stream>>>(t2buf, wb2b, biasp + 128, hbuf,    sumbuf, 0, 0);
    conv_lds<32, 1, 1, 1, 16, false, 3><<<GB, 256, 0, stream>>>(sumbuf, wbf, biasp + 160, nullptr, d_out,  0, 0);
}

// Round 8
// 1163.291 us; speedup vs baseline: 15.9593x; 1.2363x over previous
//
#include <hip/hip_runtime.h>
#include <hip/hip_bf16.h>
#include <cstddef>

typedef __hip_bfloat16 bf16;
typedef __attribute__((ext_vector_type(8))) short short8;   // 8 bf16 = one MFMA A/B frag
typedef __attribute__((ext_vector_type(4))) float f32x4;    // MFMA 16x16 accumulator

constexpr int H = 80, W = 96, T = 112;
constexpr int N = H * W * T;               // 860160
constexpr int WT = W * T;                  // 10752
constexpr int Hh = 40, Wh = 48, Th = 56;
constexpr int Nh = Hh * Wh * Th;
constexpr int PH = 84, PW = 100, PT = 116;
constexpr int NPF = PH * PW * PT;          // 974400

static __device__ __forceinline__ float b2f(bf16 v) { return __bfloat162float(v); }
static __device__ __forceinline__ bf16  f2b(float v) { return __float2bfloat16(v); }

// ================= weight build: w[COUT][CIN][27] f32 -> frag-order bf16 =================
__global__ __launch_bounds__(256) void wbuild_kernel(const float* __restrict__ w, bf16* __restrict__ wb,
                                                     int COUT, int CIN, int KC_TOT, int NT_TOT)
{
    int idx = blockIdx.x * 256 + threadIdx.x;
    int total = 27 * KC_TOT * NT_TOT * 512;
    if (idx >= total) return;
    int j    = idx & 7;
    int lane = (idx >> 3) & 63;
    int rest = idx >> 9;
    int nt   = rest % NT_TOT; rest /= NT_TOT;
    int kc   = rest % KC_TOT;
    int tap  = rest / KC_TOT;
    int o    = nt * 16 + (lane & 15);
    int cin  = kc * 32 + (lane >> 4) * 8 + j;
    float val = (o < COUT && cin < CIN) ? w[((size_t)o * CIN + cin) * 27 + tap] : 0.f;
    wb[idx] = f2b(val);
}

// ---- padded biases: [0,64) b1a | [64,96) b1b | [96,128) b2a | [128,160) b2b | [160,176) bf
__global__ __launch_bounds__(256) void bias_kernel(const float* __restrict__ b1a, const float* __restrict__ b1b,
                                                   const float* __restrict__ b2a, const float* __restrict__ b2b,
                                                   const float* __restrict__ bff, float* __restrict__ out)
{
    int i = threadIdx.x;
    if (i < 64)       out[i] = (i < 59) ? b1a[i] : 0.f;
    else if (i < 96)  { int j = i - 64;  out[i] = (j < 16) ? b1b[j] : 0.f; }
    else if (i < 128) { int j = i - 96;  out[i] = (j < 16) ? b2a[j] : 0.f; }
    else if (i < 160) { int j = i - 128; out[i] = (j < 16) ? b2b[j] : 0.f; }
    else if (i < 176) { int j = i - 160; out[i] = (j < 3)  ? bff[j] : 0.f; }
}

// ================= pre-conv pipeline =================
__global__ __launch_bounds__(256) void upsample_kernel(const float* __restrict__ flow,
                                                       float* __restrict__ flow_up)
{
    int idx = blockIdx.x * 256 + threadIdx.x;
    if (idx >= 3 * N) return;
    int c = idx / N, v = idx % N;
    int t = v % T; int hw = v / T; int w = hw % W; int h = hw / W;
    float ph = (float)h * ((float)(Hh - 1) / (float)(H - 1));
    float pw = (float)w * ((float)(Wh - 1) / (float)(W - 1));
    float pt = (float)t * ((float)(Th - 1) / (float)(T - 1));
    int i0 = min((int)ph, Hh - 2); float fh = ph - (float)i0;
    int j0 = min((int)pw, Wh - 2); float fw = pw - (float)j0;
    int k0 = min((int)pt, Th - 2); float ft = pt - (float)k0;
    const float* fp = flow + (size_t)c * Nh;
    auto L = [&](int a, int b, int d) -> float {
        return 2.0f * fp[((size_t)a * Wh + b) * Th + d];
    };
    float v000 = L(i0, j0, k0),     v001 = L(i0, j0, k0 + 1);
    float v010 = L(i0, j0 + 1, k0), v011 = L(i0, j0 + 1, k0 + 1);
    float v100 = L(i0 + 1, j0, k0),     v101 = L(i0 + 1, j0, k0 + 1);
    float v110 = L(i0 + 1, j0 + 1, k0), v111 = L(i0 + 1, j0 + 1, k0 + 1);
    float val = (1.f - fh) * ((1.f - fw) * ((1.f - ft) * v000 + ft * v001)
                            +        fw  * ((1.f - ft) * v010 + ft * v011))
              +        fh  * ((1.f - fw) * ((1.f - ft) * v100 + ft * v101)
                            +        fw  * ((1.f - ft) * v110 + ft * v111));
    flow_up[idx] = val;
}

// warp -> xw planar bf16 [16][N]
__global__ __launch_bounds__(256) void warp_kernel(const float* __restrict__ x,
                                                   const float* __restrict__ flow_up,
                                                   bf16* __restrict__ xw)
{
    int v = blockIdx.x * 256 + threadIdx.x;
    if (v >= N) return;
    int t = v % T; int hw = v / T; int w = hw % W; int h = hw / W;
    float cx = (float)h + flow_up[v];
    float cy = (float)w + flow_up[N + v];
    float cz = (float)t + flow_up[2 * N + v];
    float fx0 = floorf(cx), fy0 = floorf(cy), fz0 = floorf(cz);
    float fx = cx - fx0, fy = cy - fy0, fz = cz - fz0;
    int ix = (int)fx0, iy = (int)fy0, iz = (int)fz0;

    float wc[8];
    int   oc[8];
    #pragma unroll
    for (int c8 = 0; c8 < 8; c8++) {
        int dx = (c8 >> 2) & 1, dy = (c8 >> 1) & 1, dz = c8 & 1;
        int ax = ix + dx, ay = iy + dy, az = iz + dz;
        bool ok = ((unsigned)ax < (unsigned)H) && ((unsigned)ay < (unsigned)W) && ((unsigned)az < (unsigned)T);
        float wt = (dx ? fx : 1.f - fx) * (dy ? fy : 1.f - fy) * (dz ? fz : 1.f - fz);
        wc[c8] = ok ? wt : 0.f;
        int cax = min(max(ax, 0), H - 1);
        int cay = min(max(ay, 0), W - 1);
        int caz = min(max(az, 0), T - 1);
        oc[c8] = (cax * W + cay) * T + caz;
    }
    #pragma unroll 1
    for (int c = 0; c < 16; c++) {
        const float* xp = x + (size_t)c * N;
        float s = 0.f;
        #pragma unroll
        for (int c8 = 0; c8 < 8; c8++) s += wc[c8] * xp[oc[c8]];
        xw[(size_t)c * N + v] = f2b(s);
    }
}

__global__ __launch_bounds__(256) void pm_kernel(const bf16* __restrict__ xw, bf16* __restrict__ pm)
{
    int idx = blockIdx.x * 256 + threadIdx.x;
    if (idx >= 16 * N) return;
    int c = idx / N, v = idx % N;
    int t = v % T; int hw = v / T; int w = hw % W; int h = hw / W;
    const bf16* ip = xw + (size_t)c * N;
    float s = 0.f;
    #pragma unroll
    for (int dh = -1; dh <= 1; dh++)
    #pragma unroll
    for (int dw = -1; dw <= 1; dw++)
    #pragma unroll
    for (int dt = -1; dt <= 1; dt++) {
        int hh = h + dh, ww = w + dw, tt = t + dt;
        bool ok = ((unsigned)hh < (unsigned)H) && ((unsigned)ww < (unsigned)W) && ((unsigned)tt < (unsigned)T);
        int off = ok ? ((hh * W + ww) * T + tt) : 0;
        s += ok ? b2f(ip[off]) : 0.f;
    }
    pm[idx] = f2b(s);
}

__global__ __launch_bounds__(256) void pf_kernel(const float* __restrict__ y, bf16* __restrict__ pf)
{
    int idx = blockIdx.x * 256 + threadIdx.x;
    if (idx >= 16 * NPF) return;
    int c = idx / NPF, r = idx % NPF;
    int d = r % PT; int ab = r / PT; int b = ab % PW; int a = ab / PW;
    const float* ip = y + (size_t)c * N;
    float s = 0.f;
    #pragma unroll
    for (int da = 0; da < 3; da++)
    #pragma unroll
    for (int db = 0; db < 3; db++)
    #pragma unroll
    for (int dd = 0; dd < 3; dd++) {
        int hh = a - 3 + da, ww = b - 3 + db, tt = d - 3 + dd;
        bool ok = ((unsigned)hh < (unsigned)H) && ((unsigned)ww < (unsigned)W) && ((unsigned)tt < (unsigned)T);
        int off = ok ? ((hh * W + ww) * T + tt) : 0;
        s += ok ? ip[off] : 0.f;
    }
    pf[idx] = f2b(s);
}

// ===== FUSED corr + assemble (BIG path): acc[27] in registers, one 128-B row write per voxel =====
// stack_cl[v][64]: ch0..15=xw, 16..42=corr, 43..58=y, 59..63=0
__global__ __launch_bounds__(256) void corr_assemble_kernel(const bf16* __restrict__ pm,
                                                            const bf16* __restrict__ pf,
                                                            const bf16* __restrict__ xw,
                                                            const float* __restrict__ y,
                                                            bf16* __restrict__ stack)
{
    int v = blockIdx.x * 256 + threadIdx.x;
    if (v >= N) return;
    int t = v % T; int hw = v / T; int w = hw % W; int h = hw / W;

    float pmv[16];
    #pragma unroll
    for (int c = 0; c < 16; c++) pmv[c] = b2f(pm[(size_t)c * N + v]);

    float acc[27];
    #pragma unroll
    for (int i = 0; i < 27; i++) acc[i] = 0.f;

    const size_t pbase = ((size_t)h * PW + w) * PT + t;
    #pragma unroll 1
    for (int c = 0; c < 16; c++) {
        const bf16* pfc = pf + (size_t)c * NPF + pbase;
        float pv = pmv[c];
        #pragma unroll
        for (int i = 0; i < 3; i++)
            #pragma unroll
            for (int j = 0; j < 3; j++)
                #pragma unroll
                for (int k = 0; k < 3; k++)
                    acc[i * 9 + j * 3 + k] += pv * b2f(pfc[((size_t)(2 * i) * PW + 2 * j) * PT + 2 * k]);
    }

    unsigned short ch[64];
    #pragma unroll
    for (int c = 0; c < 16; c++) ch[c] = ((const unsigned short*)xw)[(size_t)c * N + v];
    #pragma unroll
    for (int i = 0; i < 27; i++) { bf16 b = f2b(acc[i] * (1.f / 27.f)); ch[16 + i] = *(unsigned short*)&b; }
    #pragma unroll
    for (int c = 0; c < 16; c++) { bf16 b = f2b(y[(size_t)c * N + v]); ch[43 + c] = *(unsigned short*)&b; }
    #pragma unroll
    for (int c = 59; c < 64; c++) ch[c] = 0;
    uint4* dst = (uint4*)((unsigned short*)stack + (size_t)v * 64);
    #pragma unroll
    for (int k = 0; k < 8; k++) dst[k] = ((uint4*)ch)[k];
}

// ---- old two-kernel corr/assemble (SMALL fallback path only) ----
__global__ __launch_bounds__(256) void corr_kernel(const bf16* __restrict__ pm, const bf16* __restrict__ pf,
                                                   bf16* __restrict__ corr_tmp)
{
    int v = blockIdx.x * 256 + threadIdx.x;
    if (v >= N) return;
    int t = v % T; int hw = v / T; int w = hw % W; int h = hw / W;
    float pmv[16];
    #pragma unroll
    for (int c = 0; c < 16; c++) pmv[c] = b2f(pm[(size_t)c * N + v]);
    #pragma unroll 1
    for (int i = 0; i < 3; i++)
    #pragma unroll 1
    for (int j = 0; j < 3; j++)
    #pragma unroll 1
    for (int k = 0; k < 3; k++) {
        size_t base = ((size_t)(2 * i + h) * PW + (2 * j + w)) * PT + (2 * k + t);
        float s = 0.f;
        #pragma unroll
        for (int c = 0; c < 16; c++) s += pmv[c] * b2f(pf[(size_t)c * NPF + base]);
        corr_tmp[(size_t)v * 28 + (i * 9 + j * 3 + k)] = f2b(s * (1.f / 27.f));
    }
}

__global__ __launch_bounds__(256) void assemble_kernel(const bf16* __restrict__ xw,
                                                       const bf16* __restrict__ corr_tmp,
                                                       const float* __restrict__ y,
                                                       bf16* __restrict__ stack)
{
    int v = blockIdx.x * 256 + threadIdx.x;
    if (v >= N) return;
    unsigned short ch[64];
    #pragma unroll
    for (int c = 0; c < 16; c++) ch[c] = ((const unsigned short*)xw)[(size_t)c * N + v];
    #pragma unroll
    for (int i = 0; i < 27; i++) ch[16 + i] = ((const unsigned short*)corr_tmp)[(size_t)v * 28 + i];
    #pragma unroll
    for (int c = 0; c < 16; c++) { bf16 b = f2b(y[(size_t)c * N + v]); ch[43 + c] = *(unsigned short*)&b; }
    #pragma unroll
    for (int c = 59; c < 64; c++) ch[c] = 0;
    uint4* dst = (uint4*)((unsigned short*)stack + (size_t)v * 64);
    #pragma unroll
    for (int k = 0; k < 8; k++) dst[k] = ((uint4*)ch)[k];
}

// ================= MFMA implicit-GEMM conv with LDS A-halo (round-7, proven) =================
template <int CST_IN, int KC_TOT, int NT, int NT_TOT, int CST_OUT, bool RELU, int STORE>
__global__ __launch_bounds__(256, 3) void conv_lds(const bf16* __restrict__ in,
                                                   const bf16* __restrict__ wb,
                                                   const float* __restrict__ bias,
                                                   const bf16* __restrict__ aux,
                                                   void* __restrict__ out,
                                                   int kc_off, int nt_off)
{
    constexpr int KCP     = CST_IN / 32;   // internal kc passes
    constexpr int ASTRIDE = 80;            // 64B data + 16B pad per halo slot
    constexpr int ZOFF    = 648 * ASTRIDE; // zero slot
    __shared__ __align__(16) char smem[648 * ASTRIDE + 16];

    const int tid  = threadIdx.x;
    const int lane = tid & 63;
    const int n16  = lane & 15;
    const int q    = lane >> 4;
    const int wv   = tid >> 6;

    int bid = blockIdx.x;
    int cid = (bid & 7) * 420 + (bid >> 3);
    int t0  = (cid % 7) * 16;
    int rs  = cid / 7;
    int w0  = (rs % 24) * 4;
    int h0  = (rs / 24) * 4;
    const int h = h0 + wv;

    unsigned msk[4];
    #pragma unroll
    for (int m2 = 0; m2 < 4; ++m2) {
        int w = w0 + m2, t = t0 + n16;
        bool vh[3] = { h > 0, true, h < H - 1 };
        bool vw[3] = { w > 0, true, w < W - 1 };
        bool vt[3] = { t > 0, true, t < T - 1 };
        unsigned m = 0;
        #pragma unroll
        for (int tap = 0; tap < 27; ++tap)
            if (vh[tap / 9] && vw[(tap % 9) / 3] && vt[tap % 3]) m |= (1u << tap);
        msk[m2] = m;
    }

    f32x4 acc[4][NT];
    #pragma unroll
    for (int nt = 0; nt < NT; ++nt) {
        float bv = (STORE == 1) ? 0.f : bias[nt * 16 + n16];
        #pragma unroll
        for (int m2 = 0; m2 < 4; ++m2)
            #pragma unroll
            for (int r = 0; r < 4; ++r) acc[m2][nt][r] = bv;
    }

    if (tid < 4) *(int*)(smem + ZOFF + tid * 4) = 0;

    #pragma unroll 1
    for (int kcp = 0; kcp < KCP; ++kcp) {
        if (kcp > 0) __syncthreads();
        #pragma unroll 1
        for (int it = 0; it < 11; ++it) {
            int slot = it * 64 + (tid >> 2);
            if (slot < 648) {
                int hh = slot / 108, rm = slot - hh * 108;
                int ww = rm / 18,    tt = rm - ww * 18;
                int gh = min(max(h0 - 1 + hh, 0), H - 1);
                int gw = min(max(w0 - 1 + ww, 0), W - 1);
                int gt = min(max(t0 - 1 + tt, 0), T - 1);
                const char* gp = (const char*)in + (size_t)((gh * W + gw) * T + gt) * (CST_IN * 2)
                                 + kcp * 64 + (tid & 3) * 16;
                *(uint4*)(smem + slot * ASTRIDE + (tid & 3) * 16) = *(const uint4*)gp;
            }
        }
        __syncthreads();

        auto loadB = [&](int tap, short8 (&bv)[NT]) {
            #pragma unroll
            for (int nt = 0; nt < NT; ++nt) {
                size_t grec = (size_t)((tap * KC_TOT) + kcp + kc_off) * NT_TOT + nt + nt_off;
                bv[nt] = *(const short8*)((const char*)wb + grec * 1024 + (size_t)lane * 16);
            }
        };
        auto tapcompute = [&](int tap, short8 (&bv)[NT]) {
            int dh = tap / 9, rr = tap - dh * 9, dw = rr / 3, dt = rr - dw * 3;
            short8 av[4];
            #pragma unroll
            for (int m2 = 0; m2 < 4; ++m2) {
                bool ok = (msk[m2] >> tap) & 1u;
                int hvox = ((wv + dh) * 6 + (m2 + dw)) * 18 + (n16 + dt);
                const char* p = ok ? (smem + hvox * ASTRIDE + q * 16) : (smem + ZOFF);
                av[m2] = *(const short8*)p;
            }
            #pragma unroll
            for (int nt = 0; nt < NT; ++nt)
                #pragma unroll
                for (int m2 = 0; m2 < 4; ++m2)
                    acc[m2][nt] = __builtin_amdgcn_mfma_f32_16x16x32_bf16(av[m2], bv[nt], acc[m2][nt], 0, 0, 0);
        };

        short8 bvA[NT], bvB[NT];
        loadB(0, bvA);
        #pragma unroll 1
        for (int tap = 0; tap < 26; tap += 2) {
            loadB(tap + 1, bvB);
            tapcompute(tap, bvA);
            loadB(tap + 2, bvA);
            tapcompute(tap + 1, bvB);
        }
        tapcompute(26, bvA);
    }

    #pragma unroll
    for (int m2 = 0; m2 < 4; ++m2) {
        int vrow = (h * W + (w0 + m2)) * T + t0 + q * 4;
        #pragma unroll
        for (int r = 0; r < 4; ++r) {
            int v = vrow + r;
            #pragma unroll
            for (int nt = 0; nt < NT; ++nt) {
                float x = acc[m2][nt][r];
                if (STORE == 2 && nt == 0) x += b2f(aux[(size_t)v * 16 + n16]);
                if (RELU && STORE != 4) x = fmaxf(x, 0.f);
                if (STORE == 4) x = fmaxf(x, 0.f) + b2f(aux[(size_t)v * CST_OUT + nt * 16 + n16]);
                if (STORE == 1) {
                    if (nt == 0) ((bf16*)out)[(size_t)v * 16 + n16] = f2b(x);
                } else if (STORE == 3) {
                    int ch = nt * 16 + n16;
                    if (ch < 3) ((float*)out)[(size_t)ch * N + v] = x;
                } else {
                    ((bf16*)out)[(size_t)v * CST_OUT + nt * 16 + n16] = f2b(x);
                }
            }
        }
    }
}

extern "C" void kernel_launch(void* const* d_in, const int* in_sizes, int n_in,
                              void* d_out, int out_size, void* d_ws, size_t ws_size,
                              hipStream_t stream)
{
    (void)in_sizes; (void)n_in; (void)out_size;
    const float* x_p   = (const float*)d_in[0];
    const float* y_p   = (const float*)d_in[1];
    const float* flow_p= (const float*)d_in[2];
    const float* w1a_p = (const float*)d_in[3];
    const float* b1a_p = (const float*)d_in[4];
    const float* w1b_p = (const float*)d_in[5];
    const float* b1b_p = (const float*)d_in[6];
    const float* w2a_p = (const float*)d_in[7];
    const float* b2a_p = (const float*)d_in[8];
    const float* w2b_p = (const float*)d_in[9];
    const float* b2b_p = (const float*)d_in[10];
    const float* wf_p  = (const float*)d_in[11];
    const float* bf_p  = (const float*)d_in[12];

    char* wsb = (char*)d_ws;
    const size_t NB32 = (size_t)N * 32 * 2;          // 55,050,240
    const size_t NB64 = 2 * NB32;                    // 110,100,480
    const size_t WSUM = (110592 + 55296 + 27648 + 27648 + 13824);
    const size_t NEED_BIG = 2 * NB64 + WSUM * 2 + 176 * 4 + 256;  // 220,671,936
    const bool BIG = (ws_size >= NEED_BIG);

    bf16 *stack, *buf1, *pm, *pf, *xw, *corr_tmp, *hbuf, *t2buf, *sumbuf, *hpart, *buf1h;
    float* flow_up; bf16* wroot;
    if (BIG) {
        // Region A [0, NB64): flow_up transient, then stack[N][64] (fused-kernel output),
        //   then hbuf[N][32]@0 + t2buf[N][32]@NB32 after stack dies.
        // Region B [NB64, 2*NB64): xw(27.5M) | pm(27.5M) | pf(31.2M) transients -> buf1[N][64]
        //   -> sumbuf[N][32] after buf1 dies.
        stack    = (bf16*)wsb;
        flow_up  = (float*)wsb;
        hbuf     = (bf16*)wsb;
        t2buf    = (bf16*)(wsb + NB32);
        buf1     = (bf16*)(wsb + NB64);
        xw       = (bf16*)(wsb + NB64);
        pm       = (bf16*)(wsb + NB64 + (size_t)16 * N * 2);
        pf       = (bf16*)(wsb + NB64 + (size_t)32 * N * 2);
        sumbuf   = (bf16*)(wsb + NB64);
        corr_tmp = nullptr; hpart = nullptr; buf1h = nullptr;
        wroot    = (bf16*)(wsb + 2 * NB64);
    } else {
        const size_t A_off = 0, B_off = 2 * NB32, C_off = 3 * NB32;
        const size_t D_off = C_off + (size_t)N * 16 * 2;
        pf       = (bf16*)(wsb + A_off);
        pm       = (bf16*)(wsb + A_off + (size_t)16 * NPF * 2);
        flow_up  = (float*)(wsb + A_off + (size_t)16 * NPF * 2 + (size_t)16 * N * 2);
        stack    = (bf16*)(wsb + A_off);
        hbuf     = (bf16*)(wsb + A_off);
        t2buf    = (bf16*)(wsb + A_off + NB32);
        corr_tmp = (bf16*)(wsb + B_off);
        buf1h    = (bf16*)(wsb + B_off);
        sumbuf   = (bf16*)(wsb + B_off);
        xw       = (bf16*)(wsb + C_off);
        hpart    = (bf16*)(wsb + C_off);
        buf1     = nullptr;
        wroot    = (bf16*)(wsb + D_off);
    }
    bf16*  wb1a  = wroot;
    bf16*  wb1b  = wb1a + 110592;
    bf16*  wb2a  = wb1b + 55296;
    bf16*  wb2b  = wb2a + 27648;
    bf16*  wbf   = wb2b + 27648;
    float* biasp = (float*)(wbf + 13824);

    wbuild_kernel<<<432, 256, 0, stream>>>(w1a_p, wb1a, 59, 59, 2, 4);
    wbuild_kernel<<<216, 256, 0, stream>>>(w1b_p, wb1b, 16, 59, 2, 2);
    wbuild_kernel<<<108, 256, 0, stream>>>(w2a_p, wb2a, 16, 16, 1, 2);
    wbuild_kernel<<<108, 256, 0, stream>>>(w2b_p, wb2b, 16, 16, 1, 2);
    wbuild_kernel<<<54,  256, 0, stream>>>(wf_p,  wbf,  3,  16, 1, 1);
    bias_kernel<<<1, 256, 0, stream>>>(b1a_p, b1b_p, b2a_p, b2b_p, bf_p, biasp);

    upsample_kernel<<<3 * N / 256, 256, 0, stream>>>(flow_p, flow_up);
    warp_kernel<<<N / 256, 256, 0, stream>>>(x_p, flow_up, xw);
    pm_kernel<<<16 * N / 256, 256, 0, stream>>>(xw, pm);
    pf_kernel<<<16 * NPF / 256, 256, 0, stream>>>(y_p, pf);
    if (BIG) {
        corr_assemble_kernel<<<N / 256, 256, 0, stream>>>(pm, pf, xw, y_p, stack);
    } else {
        corr_kernel<<<N / 256, 256, 0, stream>>>(pm, pf, corr_tmp);
        assemble_kernel<<<N / 256, 256, 0, stream>>>(xw, corr_tmp, y_p, stack);
    }

    const int GB = N / 256;  // 3360 brick blocks
    if (BIG) {
        conv_lds<64, 2, 4, 4, 64, false, 0><<<GB, 256, 0, stream>>>(stack, wb1a, biasp + 0,   nullptr, buf1,  0, 0);
        conv_lds<64, 2, 2, 2, 32, true,  0><<<GB, 256, 0, stream>>>(buf1,  wb1b, biasp + 64,  nullptr, hbuf,  0, 0);
    } else {
        conv_lds<64, 2, 2, 4, 32, false, 0><<<GB, 256, 0, stream>>>(stack, wb1a, biasp + 0,   nullptr, buf1h, 0, 0);
        conv_lds<32, 2, 2, 2, 32, false, 1><<<GB, 256, 0, stream>>>(buf1h, wb1b, biasp,       nullptr, hpart, 0, 0);
        conv_lds<64, 2, 2, 4, 32, false, 0><<<GB, 256, 0, stream>>>(stack, wb1a, biasp + 32,  nullptr, buf1h, 0, 2);
        conv_lds<32, 2, 2, 2, 32, true,  2><<<GB, 256, 0, stream>>>(buf1h, wb1b, biasp + 64,  hpart,   hbuf,  1, 0);
    }
    conv_lds<32, 1, 2, 2, 32, false, 0><<<GB, 256, 0, stream>>>(hbuf,  wb2a, biasp + 96,  nullptr, t2buf,  0, 0);
    conv_lds<32, 1, 2, 2, 32, false, 4><<<GB, 256, 0, stream>>>(t2buf, wb2b, biasp + 128, hbuf,    sumbuf, 0, 0);
    conv_lds<32, 1, 1, 1, 16, false, 3><<<GB, 256, 0, stream>>>(sumbuf, wbf, biasp + 160, nullptr, d_out,  0, 0);
}

// Round 9
// 987.010 us; speedup vs baseline: 18.8096x; 1.1786x over previous
//
#include <hip/hip_runtime.h>
#include <hip/hip_bf16.h>
#include <cstddef>

typedef __hip_bfloat16 bf16;
typedef __attribute__((ext_vector_type(8))) short short8;   // 8 bf16 = one MFMA A/B frag
typedef __attribute__((ext_vector_type(4))) float f32x4;    // MFMA 16x16 accumulator

constexpr int H = 80, W = 96, T = 112;
constexpr int N = H * W * T;               // 860160
constexpr int WT = W * T;                  // 10752
constexpr int Hh = 40, Wh = 48, Th = 56;
constexpr int Nh = Hh * Wh * Th;
constexpr int PH = 84, PW = 100, PT = 116;
constexpr int NPF = PH * PW * PT;          // 974400

static __device__ __forceinline__ float b2f(bf16 v) { return __bfloat162float(v); }
static __device__ __forceinline__ bf16  f2b(float v) { return __float2bfloat16(v); }
static __device__ __forceinline__ float us2f(unsigned short u) { return __uint_as_float(((unsigned)u) << 16); }

// ================= weight build: w[COUT][CIN][27] f32 -> frag-order bf16 =================
__global__ __launch_bounds__(256) void wbuild_kernel(const float* __restrict__ w, bf16* __restrict__ wb,
                                                     int COUT, int CIN, int KC_TOT, int NT_TOT)
{
    int idx = blockIdx.x * 256 + threadIdx.x;
    int total = 27 * KC_TOT * NT_TOT * 512;
    if (idx >= total) return;
    int j    = idx & 7;
    int lane = (idx >> 3) & 63;
    int rest = idx >> 9;
    int nt   = rest % NT_TOT; rest /= NT_TOT;
    int kc   = rest % KC_TOT;
    int tap  = rest / KC_TOT;
    int o    = nt * 16 + (lane & 15);
    int cin  = kc * 32 + (lane >> 4) * 8 + j;
    float val = (o < COUT && cin < CIN) ? w[((size_t)o * CIN + cin) * 27 + tap] : 0.f;
    wb[idx] = f2b(val);
}

// ---- padded biases: [0,64) b1a | [64,96) b1b | [96,128) b2a | [128,160) b2b | [160,176) bf
__global__ __launch_bounds__(256) void bias_kernel(const float* __restrict__ b1a, const float* __restrict__ b1b,
                                                   const float* __restrict__ b2a, const float* __restrict__ b2b,
                                                   const float* __restrict__ bff, float* __restrict__ out)
{
    int i = threadIdx.x;
    if (i < 64)       out[i] = (i < 59) ? b1a[i] : 0.f;
    else if (i < 96)  { int j = i - 64;  out[i] = (j < 16) ? b1b[j] : 0.f; }
    else if (i < 128) { int j = i - 96;  out[i] = (j < 16) ? b2a[j] : 0.f; }
    else if (i < 160) { int j = i - 128; out[i] = (j < 16) ? b2b[j] : 0.f; }
    else if (i < 176) { int j = i - 160; out[i] = (j < 3)  ? bff[j] : 0.f; }
}

// ================= pre-conv pipeline =================
__global__ __launch_bounds__(256) void upsample_kernel(const float* __restrict__ flow,
                                                       float* __restrict__ flow_up)
{
    int idx = blockIdx.x * 256 + threadIdx.x;
    if (idx >= 3 * N) return;
    int c = idx / N, v = idx % N;
    int t = v % T; int hw = v / T; int w = hw % W; int h = hw / W;
    float ph = (float)h * ((float)(Hh - 1) / (float)(H - 1));
    float pw = (float)w * ((float)(Wh - 1) / (float)(W - 1));
    float pt = (float)t * ((float)(Th - 1) / (float)(T - 1));
    int i0 = min((int)ph, Hh - 2); float fh = ph - (float)i0;
    int j0 = min((int)pw, Wh - 2); float fw = pw - (float)j0;
    int k0 = min((int)pt, Th - 2); float ft = pt - (float)k0;
    const float* fp = flow + (size_t)c * Nh;
    auto L = [&](int a, int b, int d) -> float {
        return 2.0f * fp[((size_t)a * Wh + b) * Th + d];
    };
    float v000 = L(i0, j0, k0),     v001 = L(i0, j0, k0 + 1);
    float v010 = L(i0, j0 + 1, k0), v011 = L(i0, j0 + 1, k0 + 1);
    float v100 = L(i0 + 1, j0, k0),     v101 = L(i0 + 1, j0, k0 + 1);
    float v110 = L(i0 + 1, j0 + 1, k0), v111 = L(i0 + 1, j0 + 1, k0 + 1);
    float val = (1.f - fh) * ((1.f - fw) * ((1.f - ft) * v000 + ft * v001)
                            +        fw  * ((1.f - ft) * v010 + ft * v011))
              +        fh  * ((1.f - fw) * ((1.f - ft) * v100 + ft * v101)
                            +        fw  * ((1.f - ft) * v110 + ft * v111));
    flow_up[idx] = val;
}

// warp -> xw planar bf16 [16][N]
__global__ __launch_bounds__(256) void warp_kernel(const float* __restrict__ x,
                                                   const float* __restrict__ flow_up,
                                                   bf16* __restrict__ xw)
{
    int v = blockIdx.x * 256 + threadIdx.x;
    if (v >= N) return;
    int t = v % T; int hw = v / T; int w = hw % W; int h = hw / W;
    float cx = (float)h + flow_up[v];
    float cy = (float)w + flow_up[N + v];
    float cz = (float)t + flow_up[2 * N + v];
    float fx0 = floorf(cx), fy0 = floorf(cy), fz0 = floorf(cz);
    float fx = cx - fx0, fy = cy - fy0, fz = cz - fz0;
    int ix = (int)fx0, iy = (int)fy0, iz = (int)fz0;

    float wc[8];
    int   oc[8];
    #pragma unroll
    for (int c8 = 0; c8 < 8; c8++) {
        int dx = (c8 >> 2) & 1, dy = (c8 >> 1) & 1, dz = c8 & 1;
        int ax = ix + dx, ay = iy + dy, az = iz + dz;
        bool ok = ((unsigned)ax < (unsigned)H) && ((unsigned)ay < (unsigned)W) && ((unsigned)az < (unsigned)T);
        float wt = (dx ? fx : 1.f - fx) * (dy ? fy : 1.f - fy) * (dz ? fz : 1.f - fz);
        wc[c8] = ok ? wt : 0.f;
        int cax = min(max(ax, 0), H - 1);
        int cay = min(max(ay, 0), W - 1);
        int caz = min(max(az, 0), T - 1);
        oc[c8] = (cax * W + cay) * T + caz;
    }
    #pragma unroll 1
    for (int c = 0; c < 16; c++) {
        const float* xp = x + (size_t)c * N;
        float s = 0.f;
        #pragma unroll
        for (int c8 = 0; c8 < 8; c8++) s += wc[c8] * xp[oc[c8]];
        xw[(size_t)c * N + v] = f2b(s);
    }
}

// ===== pm = box3(xw, pad=1), strip-vectorized: 1 thread = 16 t-outputs =====
// grid: 16ch x H x W x 7 strips = N threads
__global__ __launch_bounds__(256) void pm_kernel(const bf16* __restrict__ xw, bf16* __restrict__ pm)
{
    int idx = blockIdx.x * 256 + threadIdx.x;
    int ts = idx % 7;  int r = idx / 7;
    int w  = r % W;    r /= W;
    int h  = r % H;    int c = r / H;
    int t0 = ts * 16;

    float acc[16];
    #pragma unroll
    for (int k = 0; k < 16; k++) acc[k] = 0.f;

    const bf16* base = xw + (size_t)c * N;
    #pragma unroll
    for (int dh = -1; dh <= 1; dh++)
        #pragma unroll
        for (int dw = -1; dw <= 1; dw++) {
            int hh = h + dh, ww = w + dw;
            if (((unsigned)hh < (unsigned)H) && ((unsigned)ww < (unsigned)W)) {
                const unsigned short* rp = (const unsigned short*)(base + (size_t)(hh * W + ww) * T);
                float v[18];
                v[0] = (t0 > 0) ? us2f(rp[t0 - 1]) : 0.f;
                short8 cA = *(const short8*)(rp + t0);
                short8 cB = *(const short8*)(rp + t0 + 8);
                #pragma unroll
                for (int j = 0; j < 8; j++) v[1 + j] = us2f((unsigned short)cA[j]);
                #pragma unroll
                for (int j = 0; j < 8; j++) v[9 + j] = us2f((unsigned short)cB[j]);
                v[17] = (t0 + 16 < T) ? us2f(rp[t0 + 16]) : 0.f;
                #pragma unroll
                for (int k = 0; k < 16; k++) acc[k] += v[k] + v[k + 1] + v[k + 2];
            }
        }

    unsigned short ch[16];
    #pragma unroll
    for (int k = 0; k < 16; k++) { bf16 b = f2b(acc[k]); ch[k] = *(unsigned short*)&b; }
    uint4* dst = (uint4*)((unsigned short*)pm + (size_t)c * N + (size_t)(h * W + w) * T + t0);
    dst[0] = ((uint4*)ch)[0];
    dst[1] = ((uint4*)ch)[1];
}

// ===== pf = box3(y, pad=3), strip-vectorized: 1 thread = 16 d-outputs =====
// grid: 16ch x PH x PW x 8 strips = 1,075,200 threads (d0=112 strip stores only 4)
__global__ __launch_bounds__(256) void pf_kernel(const float* __restrict__ y, bf16* __restrict__ pf)
{
    int idx = blockIdx.x * 256 + threadIdx.x;
    int ds = idx & 7;  int r = idx >> 3;
    int b  = r % PW;   r /= PW;
    int a  = r % PH;   int c = r / PH;
    int d0 = ds * 16;

    float acc[16];
    #pragma unroll
    for (int k = 0; k < 16; k++) acc[k] = 0.f;

    const float* base = y + (size_t)c * N;
    #pragma unroll
    for (int da = 0; da < 3; da++)
        #pragma unroll
        for (int db = 0; db < 3; db++) {
            int hh = a - 3 + da, ww = b - 3 + db;
            if (((unsigned)hh < (unsigned)H) && ((unsigned)ww < (unsigned)W)) {
                const float* rp = base + (size_t)(hh * W + ww) * T;
                float v[24];
                if (d0 >= 8) {          // chunk A: t = d0-8 .. d0-1 (start in [0,104] guaranteed)
                    float4 a0 = *(const float4*)(rp + d0 - 8);
                    float4 a1 = *(const float4*)(rp + d0 - 4);
                    v[0] = a0.x; v[1] = a0.y; v[2] = a0.z; v[3] = a0.w;
                    v[4] = a1.x; v[5] = a1.y; v[6] = a1.z; v[7] = a1.w;
                } else {
                    #pragma unroll
                    for (int j = 0; j < 8; j++) v[j] = 0.f;
                }
                if (d0 <= 104) {        // chunk B: t = d0 .. d0+7
                    float4 b0 = *(const float4*)(rp + d0);
                    float4 b1 = *(const float4*)(rp + d0 + 4);
                    v[8]  = b0.x; v[9]  = b0.y; v[10] = b0.z; v[11] = b0.w;
                    v[12] = b1.x; v[13] = b1.y; v[14] = b1.z; v[15] = b1.w;
                } else {
                    #pragma unroll
                    for (int j = 8; j < 16; j++) v[j] = 0.f;
                }
                if (d0 <= 96) {         // chunk C: t = d0+8 .. d0+15
                    float4 c0 = *(const float4*)(rp + d0 + 8);
                    float4 c1 = *(const float4*)(rp + d0 + 12);
                    v[16] = c0.x; v[17] = c0.y; v[18] = c0.z; v[19] = c0.w;
                    v[20] = c1.x; v[21] = c1.y; v[22] = c1.z; v[23] = c1.w;
                } else {
                    #pragma unroll
                    for (int j = 16; j < 24; j++) v[j] = 0.f;
                }
                #pragma unroll
                for (int k = 0; k < 16; k++) acc[k] += v[k + 5] + v[k + 6] + v[k + 7];
            }
        }

    unsigned short ch[16];
    #pragma unroll
    for (int k = 0; k < 16; k++) { bf16 bb = f2b(acc[k]); ch[k] = *(unsigned short*)&bb; }
    // pf rows are 8-B aligned (PT=116): store as uint2; last strip (d0=112) keeps only d<116
    uint2* dst = (uint2*)((unsigned short*)pf + (size_t)c * NPF + (size_t)(a * PW + b) * PT + d0);
    int nst = (d0 == 112) ? 1 : 4;
    #pragma unroll
    for (int k = 0; k < 4; k++) if (k < nst) dst[k] = ((uint2*)ch)[k];
}

// ===== FUSED corr + assemble (BIG path): acc[27] in registers, one 128-B row write per voxel =====
// stack_cl[v][64]: ch0..15=xw, 16..42=corr, 43..58=y, 59..63=0
__global__ __launch_bounds__(256) void corr_assemble_kernel(const bf16* __restrict__ pm,
                                                            const bf16* __restrict__ pf,
                                                            const bf16* __restrict__ xw,
                                                            const float* __restrict__ y,
                                                            bf16* __restrict__ stack)
{
    int v = blockIdx.x * 256 + threadIdx.x;
    if (v >= N) return;
    int t = v % T; int hw = v / T; int w = hw % W; int h = hw / W;

    float pmv[16];
    #pragma unroll
    for (int c = 0; c < 16; c++) pmv[c] = b2f(pm[(size_t)c * N + v]);

    float acc[27];
    #pragma unroll
    for (int i = 0; i < 27; i++) acc[i] = 0.f;

    const size_t pbase = ((size_t)h * PW + w) * PT + t;
    #pragma unroll 1
    for (int c = 0; c < 16; c++) {
        const bf16* pfc = pf + (size_t)c * NPF + pbase;
        float pv = pmv[c];
        #pragma unroll
        for (int i = 0; i < 3; i++)
            #pragma unroll
            for (int j = 0; j < 3; j++)
                #pragma unroll
                for (int k = 0; k < 3; k++)
                    acc[i * 9 + j * 3 + k] += pv * b2f(pfc[((size_t)(2 * i) * PW + 2 * j) * PT + 2 * k]);
    }

    unsigned short ch[64];
    #pragma unroll
    for (int c = 0; c < 16; c++) ch[c] = ((const unsigned short*)xw)[(size_t)c * N + v];
    #pragma unroll
    for (int i = 0; i < 27; i++) { bf16 b = f2b(acc[i] * (1.f / 27.f)); ch[16 + i] = *(unsigned short*)&b; }
    #pragma unroll
    for (int c = 0; c < 16; c++) { bf16 b = f2b(y[(size_t)c * N + v]); ch[43 + c] = *(unsigned short*)&b; }
    #pragma unroll
    for (int c = 59; c < 64; c++) ch[c] = 0;
    uint4* dst = (uint4*)((unsigned short*)stack + (size_t)v * 64);
    #pragma unroll
    for (int k = 0; k < 8; k++) dst[k] = ((uint4*)ch)[k];
}

// ---- old two-kernel corr/assemble (SMALL fallback path only) ----
__global__ __launch_bounds__(256) void corr_kernel(const bf16* __restrict__ pm, const bf16* __restrict__ pf,
                                                   bf16* __restrict__ corr_tmp)
{
    int v = blockIdx.x * 256 + threadIdx.x;
    if (v >= N) return;
    int t = v % T; int hw = v / T; int w = hw % W; int h = hw / W;
    float pmv[16];
    #pragma unroll
    for (int c = 0; c < 16; c++) pmv[c] = b2f(pm[(size_t)c * N + v]);
    #pragma unroll 1
    for (int i = 0; i < 3; i++)
    #pragma unroll 1
    for (int j = 0; j < 3; j++)
    #pragma unroll 1
    for (int k = 0; k < 3; k++) {
        size_t base = ((size_t)(2 * i + h) * PW + (2 * j + w)) * PT + (2 * k + t);
        float s = 0.f;
        #pragma unroll
        for (int c = 0; c < 16; c++) s += pmv[c] * b2f(pf[(size_t)c * NPF + base]);
        corr_tmp[(size_t)v * 28 + (i * 9 + j * 3 + k)] = f2b(s * (1.f / 27.f));
    }
}

__global__ __launch_bounds__(256) void assemble_kernel(const bf16* __restrict__ xw,
                                                       const bf16* __restrict__ corr_tmp,
                                                       const float* __restrict__ y,
                                                       bf16* __restrict__ stack)
{
    int v = blockIdx.x * 256 + threadIdx.x;
    if (v >= N) return;
    unsigned short ch[64];
    #pragma unroll
    for (int c = 0; c < 16; c++) ch[c] = ((const unsigned short*)xw)[(size_t)c * N + v];
    #pragma unroll
    for (int i = 0; i < 27; i++) ch[16 + i] = ((const unsigned short*)corr_tmp)[(size_t)v * 28 + i];
    #pragma unroll
    for (int c = 0; c < 16; c++) { bf16 b = f2b(y[(size_t)c * N + v]); ch[43 + c] = *(unsigned short*)&b; }
    #pragma unroll
    for (int c = 59; c < 64; c++) ch[c] = 0;
    uint4* dst = (uint4*)((unsigned short*)stack + (size_t)v * 64);
    #pragma unroll
    for (int k = 0; k < 8; k++) dst[k] = ((uint4*)ch)[k];
}

// ================= MFMA implicit-GEMM conv with LDS A-halo (round-7, proven) =================
template <int CST_IN, int KC_TOT, int NT, int NT_TOT, int CST_OUT, bool RELU, int STORE>
__global__ __launch_bounds__(256, 3) void conv_lds(const bf16* __restrict__ in,
                                                   const bf16* __restrict__ wb,
                                                   const float* __restrict__ bias,
                                                   const bf16* __restrict__ aux,
                                                   void* __restrict__ out,
                                                   int kc_off, int nt_off)
{
    constexpr int KCP     = CST_IN / 32;   // internal kc passes
    constexpr int ASTRIDE = 80;            // 64B data + 16B pad per halo slot
    constexpr int ZOFF    = 648 * ASTRIDE; // zero slot
    __shared__ __align__(16) char smem[648 * ASTRIDE + 16];

    const int tid  = threadIdx.x;
    const int lane = tid & 63;
    const int n16  = lane & 15;
    const int q    = lane >> 4;
    const int wv   = tid >> 6;

    int bid = blockIdx.x;
    int cid = (bid & 7) * 420 + (bid >> 3);
    int t0  = (cid % 7) * 16;
    int rs  = cid / 7;
    int w0  = (rs % 24) * 4;
    int h0  = (rs / 24) * 4;
    const int h = h0 + wv;

    unsigned msk[4];
    #pragma unroll
    for (int m2 = 0; m2 < 4; ++m2) {
        int w = w0 + m2, t = t0 + n16;
        bool vh[3] = { h > 0, true, h < H - 1 };
        bool vw[3] = { w > 0, true, w < W - 1 };
        bool vt[3] = { t > 0, true, t < T - 1 };
        unsigned m = 0;
        #pragma unroll
        for (int tap = 0; tap < 27; ++tap)
            if (vh[tap / 9] && vw[(tap % 9) / 3] && vt[tap % 3]) m |= (1u << tap);
        msk[m2] = m;
    }

    f32x4 acc[4][NT];
    #pragma unroll
    for (int nt = 0; nt < NT; ++nt) {
        float bv = (STORE == 1) ? 0.f : bias[nt * 16 + n16];
        #pragma unroll
        for (int m2 = 0; m2 < 4; ++m2)
            #pragma unroll
            for (int r = 0; r < 4; ++r) acc[m2][nt][r] = bv;
    }

    if (tid < 4) *(int*)(smem + ZOFF + tid * 4) = 0;

    #pragma unroll 1
    for (int kcp = 0; kcp < KCP; ++kcp) {
        if (kcp > 0) __syncthreads();
        #pragma unroll 1
        for (int it = 0; it < 11; ++it) {
            int slot = it * 64 + (tid >> 2);
            if (slot < 648) {
                int hh = slot / 108, rm = slot - hh * 108;
                int ww = rm / 18,    tt = rm - ww * 18;
                int gh = min(max(h0 - 1 + hh, 0), H - 1);
                int gw = min(max(w0 - 1 + ww, 0), W - 1);
                int gt = min(max(t0 - 1 + tt, 0), T - 1);
                const char* gp = (const char*)in + (size_t)((gh * W + gw) * T + gt) * (CST_IN * 2)
                                 + kcp * 64 + (tid & 3) * 16;
                *(uint4*)(smem + slot * ASTRIDE + (tid & 3) * 16) = *(const uint4*)gp;
            }
        }
        __syncthreads();

        auto loadB = [&](int tap, short8 (&bv)[NT]) {
            #pragma unroll
            for (int nt = 0; nt < NT; ++nt) {
                size_t grec = (size_t)((tap * KC_TOT) + kcp + kc_off) * NT_TOT + nt + nt_off;
                bv[nt] = *(const short8*)((const char*)wb + grec * 1024 + (size_t)lane * 16);
            }
        };
        auto tapcompute = [&](int tap, short8 (&bv)[NT]) {
            int dh = tap / 9, rr = tap - dh * 9, dw = rr / 3, dt = rr - dw * 3;
            short8 av[4];
            #pragma unroll
            for (int m2 = 0; m2 < 4; ++m2) {
                bool ok = (msk[m2] >> tap) & 1u;
                int hvox = ((wv + dh) * 6 + (m2 + dw)) * 18 + (n16 + dt);
                const char* p = ok ? (smem + hvox * ASTRIDE + q * 16) : (smem + ZOFF);
                av[m2] = *(const short8*)p;
            }
            #pragma unroll
            for (int nt = 0; nt < NT; ++nt)
                #pragma unroll
                for (int m2 = 0; m2 < 4; ++m2)
                    acc[m2][nt] = __builtin_amdgcn_mfma_f32_16x16x32_bf16(av[m2], bv[nt], acc[m2][nt], 0, 0, 0);
        };

        short8 bvA[NT], bvB[NT];
        loadB(0, bvA);
        #pragma unroll 1
        for (int tap = 0; tap < 26; tap += 2) {
            loadB(tap + 1, bvB);
            tapcompute(tap, bvA);
            loadB(tap + 2, bvA);
            tapcompute(tap + 1, bvB);
        }
        tapcompute(26, bvA);
    }

    #pragma unroll
    for (int m2 = 0; m2 < 4; ++m2) {
        int vrow = (h * W + (w0 + m2)) * T + t0 + q * 4;
        #pragma unroll
        for (int r = 0; r < 4; ++r) {
            int v = vrow + r;
            #pragma unroll
            for (int nt = 0; nt < NT; ++nt) {
                float x = acc[m2][nt][r];
                if (STORE == 2 && nt == 0) x += b2f(aux[(size_t)v * 16 + n16]);
                if (RELU && STORE != 4) x = fmaxf(x, 0.f);
                if (STORE == 4) x = fmaxf(x, 0.f) + b2f(aux[(size_t)v * CST_OUT + nt * 16 + n16]);
                if (STORE == 1) {
                    if (nt == 0) ((bf16*)out)[(size_t)v * 16 + n16] = f2b(x);
                } else if (STORE == 3) {
                    int ch = nt * 16 + n16;
                    if (ch < 3) ((float*)out)[(size_t)ch * N + v] = x;
                } else {
                    ((bf16*)out)[(size_t)v * CST_OUT + nt * 16 + n16] = f2b(x);
                }
            }
        }
    }
}

extern "C" void kernel_launch(void* const* d_in, const int* in_sizes, int n_in,
                              void* d_out, int out_size, void* d_ws, size_t ws_size,
                              hipStream_t stream)
{
    (void)in_sizes; (void)n_in; (void)out_size;
    const float* x_p   = (const float*)d_in[0];
    const float* y_p   = (const float*)d_in[1];
    const float* flow_p= (const float*)d_in[2];
    const float* w1a_p = (const float*)d_in[3];
    const float* b1a_p = (const float*)d_in[4];
    const float* w1b_p = (const float*)d_in[5];
    const float* b1b_p = (const float*)d_in[6];
    const float* w2a_p = (const float*)d_in[7];
    const float* b2a_p = (const float*)d_in[8];
    const float* w2b_p = (const float*)d_in[9];
    const float* b2b_p = (const float*)d_in[10];
    const float* wf_p  = (const float*)d_in[11];
    const float* bf_p  = (const float*)d_in[12];

    char* wsb = (char*)d_ws;
    const size_t NB32 = (size_t)N * 32 * 2;          // 55,050,240
    const size_t NB64 = 2 * NB32;                    // 110,100,480
    const size_t WSUM = (110592 + 55296 + 27648 + 27648 + 13824);
    const size_t NEED_BIG = 2 * NB64 + WSUM * 2 + 176 * 4 + 256;  // 220,671,936
    const bool BIG = (ws_size >= NEED_BIG);

    bf16 *stack, *buf1, *pm, *pf, *xw, *corr_tmp, *hbuf, *t2buf, *sumbuf, *hpart, *buf1h;
    float* flow_up; bf16* wroot;
    if (BIG) {
        stack    = (bf16*)wsb;
        flow_up  = (float*)wsb;
        hbuf     = (bf16*)wsb;
        t2buf    = (bf16*)(wsb + NB32);
        buf1     = (bf16*)(wsb + NB64);
        xw       = (bf16*)(wsb + NB64);
        pm       = (bf16*)(wsb + NB64 + (size_t)16 * N * 2);
        pf       = (bf16*)(wsb + NB64 + (size_t)32 * N * 2);
        sumbuf   = (bf16*)(wsb + NB64);
        corr_tmp = nullptr; hpart = nullptr; buf1h = nullptr;
        wroot    = (bf16*)(wsb + 2 * NB64);
    } else {
        const size_t A_off = 0, B_off = 2 * NB32, C_off = 3 * NB32;
        const size_t D_off = C_off + (size_t)N * 16 * 2;
        pf       = (bf16*)(wsb + A_off);
        pm       = (bf16*)(wsb + A_off + (size_t)16 * NPF * 2);
        flow_up  = (float*)(wsb + A_off + (size_t)16 * NPF * 2 + (size_t)16 * N * 2);
        stack    = (bf16*)(wsb + A_off);
        hbuf     = (bf16*)(wsb + A_off);
        t2buf    = (bf16*)(wsb + A_off + NB32);
        corr_tmp = (bf16*)(wsb + B_off);
        buf1h    = (bf16*)(wsb + B_off);
        sumbuf   = (bf16*)(wsb + B_off);
        xw       = (bf16*)(wsb + C_off);
        hpart    = (bf16*)(wsb + C_off);
        buf1     = nullptr;
        wroot    = (bf16*)(wsb + D_off);
    }
    bf16*  wb1a  = wroot;
    bf16*  wb1b  = wb1a + 110592;
    bf16*  wb2a  = wb1b + 55296;
    bf16*  wb2b  = wb2a + 27648;
    bf16*  wbf   = wb2b + 27648;
    float* biasp = (float*)(wbf + 13824);

    wbuild_kernel<<<432, 256, 0, stream>>>(w1a_p, wb1a, 59, 59, 2, 4);
    wbuild_kernel<<<216, 256, 0, stream>>>(w1b_p, wb1b, 16, 59, 2, 2);
    wbuild_kernel<<<108, 256, 0, stream>>>(w2a_p, wb2a, 16, 16, 1, 2);
    wbuild_kernel<<<108, 256, 0, stream>>>(w2b_p, wb2b, 16, 16, 1, 2);
    wbuild_kernel<<<54,  256, 0, stream>>>(wf_p,  wbf,  3,  16, 1, 1);
    bias_kernel<<<1, 256, 0, stream>>>(b1a_p, b1b_p, b2a_p, b2b_p, bf_p, biasp);

    upsample_kernel<<<3 * N / 256, 256, 0, stream>>>(flow_p, flow_up);
    warp_kernel<<<N / 256, 256, 0, stream>>>(x_p, flow_up, xw);
    pm_kernel<<<N / 256, 256, 0, stream>>>(xw, pm);                  // 3360 blocks (strip-vectorized)
    pf_kernel<<<16 * PH * PW * 8 / 256, 256, 0, stream>>>(y_p, pf);  // 4200 blocks (strip-vectorized)
    if (BIG) {
        corr_assemble_kernel<<<N / 256, 256, 0, stream>>>(pm, pf, xw, y_p, stack);
    } else {
        corr_kernel<<<N / 256, 256, 0, stream>>>(pm, pf, corr_tmp);
        assemble_kernel<<<N / 256, 256, 0, stream>>>(xw, corr_tmp, y_p, stack);
    }

    const int GB = N / 256;  // 3360 brick blocks
    if (BIG) {
        conv_lds<64, 2, 4, 4, 64, false, 0><<<GB, 256, 0, stream>>>(stack, wb1a, biasp + 0,   nullptr, buf1,  0, 0);
        conv_lds<64, 2, 2, 2, 32, true,  0><<<GB, 256, 0, stream>>>(buf1,  wb1b, biasp + 64,  nullptr, hbuf,  0, 0);
    } else {
        conv_lds<64, 2, 2, 4, 32, false, 0><<<GB, 256, 0, stream>>>(stack, wb1a, biasp + 0,   nullptr, buf1h, 0, 0);
        conv_lds<32, 2, 2, 2, 32, false, 1><<<GB, 256, 0, stream>>>(buf1h, wb1b, biasp,       nullptr, hpart, 0, 0);
        conv_lds<64, 2, 2, 4, 32, false, 0><<<GB, 256, 0, stream>>>(stack, wb1a, biasp + 32,  nullptr, buf1h, 0, 2);
        conv_lds<32, 2, 2, 2, 32, true,  2><<<GB, 256, 0, stream>>>(buf1h, wb1b, biasp + 64,  hpart,   hbuf,  1, 0);
    }
    conv_lds<32, 1, 2, 2, 32, false, 0><<<GB, 256, 0, stream>>>(hbuf,  wb2a, biasp + 96,  nullptr, t2buf,  0, 0);
    conv_lds<32, 1, 2, 2, 32, false, 4><<<GB, 256, 0, stream>>>(t2buf, wb2b, biasp + 128, hbuf,    sumbuf, 0, 0);
    conv_lds<32, 1, 1, 1, 16, false, 3><<<GB, 256, 0, stream>>>(sumbuf, wbf, biasp + 160, nullptr, d_out,  0, 0);
}